// Round 5
// baseline (3220.666 us; speedup 1.0000x reference)
//
#include <hip/hip_runtime.h>
#include <stdint.h>
#include <math.h>

// Problem constants (from reference)
constexpr int kB = 8;      // clouds
constexpr int kP = 8192;   // points per cloud
constexpr int kF = 32;     // feature dim
constexpr int kM = 2048;   // centroids per cloud (P * 0.25)
constexpr int kK = 64;     // max neighbors
constexpr int kH = 64;     // hidden dim
constexpr int kO = 128;    // output dim

// Exact-f32 squared distance matching numpy: square elementwise, then
// sequential sum ((dx2+dy2)+dz2). contract(off) forbids fma fusion so this
// matches numpy bit-for-bit regardless of -ffp-contract=fast default.
__device__ __forceinline__ float dist2(float ax, float ay, float az,
                                       float bx, float by, float bz) {
#pragma clang fp contract(off)
    float dx = ax - bx, dy = ay - by, dz = az - bz;
    return (dx * dx + dy * dy) + dz * dz;
}

// Fast variant for conservative bounds only (contraction allowed).
__device__ __forceinline__ float dist2_fast(float ax, float ay, float az,
                                            float bx, float by, float bz) {
    float dx = ax - bx, dy = ay - by, dz = az - bz;
    return dx * dx + dy * dy + dz * dz;
}

__device__ __forceinline__ unsigned int morton9(float x, float y, float z) {
    int ix = min(7, max(0, (int)(x * 8.0f)));
    int iy = min(7, max(0, (int)(y * 8.0f)));
    int iz = min(7, max(0, (int)(z * 8.0f)));
    auto sp = [](int v) {  // 3-bit spread: bits to positions 0,3,6
        return (v & 1) | ((v & 2) << 2) | ((v & 4) << 4);
    };
    return (sp(ix) << 2) | (sp(iy) << 1) | sp(iz);
}

// Wave64 max-reduce on u32 via DPP (VALU pipe, ~3 cyc/step vs ~50 for
// ds_bpermute shuffles). bound_ctrl=true -> invalid source lanes read 0;
// all inputs are >= 0 so max-with-0 is identity. Result uniform (readlane 63).
__device__ __forceinline__ unsigned int wave_max_u32(unsigned int v) {
    unsigned int t;
    t = (unsigned int)__builtin_amdgcn_update_dpp(0, (int)v, 0x111, 0xf, 0xf, true); // row_shr:1
    v = v > t ? v : t;
    t = (unsigned int)__builtin_amdgcn_update_dpp(0, (int)v, 0x112, 0xf, 0xf, true); // row_shr:2
    v = v > t ? v : t;
    t = (unsigned int)__builtin_amdgcn_update_dpp(0, (int)v, 0x114, 0xf, 0xf, true); // row_shr:4
    v = v > t ? v : t;
    t = (unsigned int)__builtin_amdgcn_update_dpp(0, (int)v, 0x118, 0xf, 0xf, true); // row_shr:8
    v = v > t ? v : t;
    t = (unsigned int)__builtin_amdgcn_update_dpp(0, (int)v, 0x142, 0xf, 0xf, true); // row_bcast:15
    v = v > t ? v : t;
    t = (unsigned int)__builtin_amdgcn_update_dpp(0, (int)v, 0x143, 0xf, 0xf, true); // row_bcast:31
    v = v > t ? v : t;
    return (unsigned int)__builtin_amdgcn_readlane((int)v, 63);
}

// ---------------------------------------------------------------------------
// Kernel 1: farthest point sampling, exact, spatially pruned, DPP-reduced.
// One block (512 threads) per cloud; 16 Morton-sorted points per thread with
// a bounding sphere for conservative skip (2e-3 margin >> f32 rounding ->
// dd provably unchanged -> bit-exact). Argmax key (dist_bits, ~orig_idx):
// wave reduce = DPP max on hi word, then DPP max on ~idx among exact ties
// (numpy first-occurrence tie-break). One barrier/iter, ping-pong partials.
// ---------------------------------------------------------------------------
__global__ __launch_bounds__(512) void fps_kernel(const float* __restrict__ pos,
                                                  float* __restrict__ cent_out) {
    const int b = blockIdx.x;
    const int tid = threadIdx.x;
    const float* pb = pos + (size_t)b * kP * 3;

    __shared__ float sxp[kP], syp[kP], szp[kP];   // SoA cloud copy (orig index)
    __shared__ unsigned short perm[kP];           // sorted slot -> orig idx
    __shared__ int cellcnt[512];
    __shared__ int ps[512];
    __shared__ unsigned long long part[2][8];     // ping-pong wave partials

    cellcnt[tid] = 0;

    // load cloud into LDS (coalesced), count Morton cells
    float tmpx[16], tmpy[16], tmpz[16];
#pragma unroll
    for (int q = 0; q < 16; ++q) {
        int i = tid + q * 512;
        tmpx[q] = pb[i * 3 + 0];
        tmpy[q] = pb[i * 3 + 1];
        tmpz[q] = pb[i * 3 + 2];
    }
    __syncthreads();   // cellcnt zeroed before atomics
#pragma unroll
    for (int q = 0; q < 16; ++q) {
        int i = tid + q * 512;
        sxp[i] = tmpx[q]; syp[i] = tmpy[q]; szp[i] = tmpz[q];
        atomicAdd(&cellcnt[morton9(tmpx[q], tmpy[q], tmpz[q])], 1);
    }
    __syncthreads();

    // exclusive prefix sum over 512 cells (Hillis-Steele)
    int v = cellcnt[tid];
    ps[tid] = v;
    __syncthreads();
    for (int d = 1; d < 512; d <<= 1) {
        int a = (tid >= d) ? ps[tid - d] : 0;
        __syncthreads();
        ps[tid] += a;
        __syncthreads();
    }
    cellcnt[tid] = ps[tid] - v;   // exclusive offset
    __syncthreads();

    // scatter: sorted order (intra-cell order non-deterministic; harmless —
    // keys use original indices and dd is per-point)
#pragma unroll
    for (int q = 0; q < 16; ++q) {
        int i = tid + q * 512;
        int slot = atomicAdd(&cellcnt[morton9(tmpx[q], tmpy[q], tmpz[q])], 1);
        perm[slot] = (unsigned short)i;
    }
    __syncthreads();

    // adopt owned 16 consecutive sorted points
    float px[16], py[16], pz[16], dd[16];
    unsigned int oidx[16];
#pragma unroll
    for (int q = 0; q < 16; ++q) {
        unsigned int o = perm[tid * 16 + q];
        oidx[q] = o;
        px[q] = sxp[o]; py[q] = syp[o]; pz[q] = szp[o];
        dd[q] = INFINITY;
    }
    // bounding sphere of owned points
    float mnx = px[0], mxx = px[0], mny = py[0], mxy = py[0], mnz = pz[0], mxz = pz[0];
#pragma unroll
    for (int q = 1; q < 16; ++q) {
        mnx = fminf(mnx, px[q]); mxx = fmaxf(mxx, px[q]);
        mny = fminf(mny, py[q]); mxy = fmaxf(mxy, py[q]);
        mnz = fminf(mnz, pz[q]); mxz = fmaxf(mxz, pz[q]);
    }
    float scx = 0.5f * (mnx + mxx), scy = 0.5f * (mny + mxy), scz = 0.5f * (mnz + mxz);
    float r2m = 0.0f;
#pragma unroll
    for (int q = 0; q < 16; ++q)
        r2m = fmaxf(r2m, dist2_fast(px[q], py[q], pz[q], scx, scy, scz));
    const float rad = sqrtf(r2m) * 1.0001f + 1e-5f;

    // first selected point: original index 0
    float lx = sxp[0], ly = syp[0], lz = szp[0];
    if (tid == 0) {
        cent_out[(size_t)(b * kM) * 3 + 0] = lx;
        cent_out[(size_t)(b * kM) * 3 + 1] = ly;
        cent_out[(size_t)(b * kM) * 3 + 2] = lz;
    }

    const int wave = tid >> 6, lane = tid & 63;
    unsigned long long key = 0ull;     // this thread's current best key
    float thresh = INFINITY;           // rad + sqrt(bv) + margin

    for (int m = 1; m < kM; ++m) {
        float d2c = dist2_fast(scx, scy, scz, lx, ly, lz);
        if (sqrtf(d2c) <= thresh) {
            // update path: refresh dd and thread-best key (exact math)
            unsigned long long k2 = 0ull;
#pragma unroll
            for (int q = 0; q < 16; ++q) {
                float d2 = dist2(px[q], py[q], pz[q], lx, ly, lz);
                float nd = fminf(dd[q], d2);
                dd[q] = nd;
                unsigned long long cand =
                    ((unsigned long long)__float_as_uint(nd) << 32) |
                    (unsigned int)(~oidx[q]);
                if (cand > k2) k2 = cand;
            }
            key = k2;
            float bv = __uint_as_float((unsigned int)(key >> 32));
            thresh = rad + sqrtf(bv) + 2e-3f;
        }

        // wave argmax: DPP max on dist bits, then DPP max on ~idx among ties
        unsigned int hi = (unsigned int)(key >> 32);
        unsigned int maxhi = wave_max_u32(hi);
        unsigned int lo = (hi == maxhi) ? (unsigned int)key : 0u;
        unsigned int maxlo = wave_max_u32(lo);
        if (lane == 0)
            part[m & 1][wave] = ((unsigned long long)maxhi << 32) | maxlo;
        __syncthreads();

        // every thread computes the block winner from the 8 partials
        unsigned long long k = part[m & 1][0];
#pragma unroll
        for (int w = 1; w < 8; ++w) {
            unsigned long long o = part[m & 1][w];
            if (o > k) k = o;
        }
        unsigned int wi = ~(unsigned int)k;        // recover original index
        lx = sxp[wi]; ly = syp[wi]; lz = szp[wi];  // broadcast reads

        if (tid == 0) {
            size_t o = (size_t)(b * kM + m) * 3;
            cent_out[o + 0] = lx;
            cent_out[o + 1] = ly;
            cent_out[o + 2] = lz;
        }
        // ping-pong part[] + next barrier order the WAR hazard
    }
}

// ---------------------------------------------------------------------------
// Kernel 2: radius ball query. One wave per centroid (4 waves / 256-thread
// block). Scan points in index order 64 at a time; ballot + prefix popcount
// assigns output slots -> lowest indices first, exactly like the reference's
// sort+take-K. Early exit once K neighbors found.
// ---------------------------------------------------------------------------
__global__ __launch_bounds__(256) void ball_kernel(const float* __restrict__ pos,
                                                   const float* __restrict__ cent,
                                                   uint16_t* __restrict__ nb,
                                                   int* __restrict__ cnt_arr,
                                                   float* __restrict__ batch_out) {
    const int wave = threadIdx.x >> 6, lane = threadIdx.x & 63;
    const int c = blockIdx.x * 4 + wave;
    const int b = c >> 11;  // c / kM
    const float R2 = (float)(0.2 * 0.2);  // same double->float rounding as reference

    float cx = cent[(size_t)c * 3 + 0];
    float cy = cent[(size_t)c * 3 + 1];
    float cz = cent[(size_t)c * 3 + 2];
    const float* pb = pos + (size_t)b * kP * 3;

    int cnt = 0;
    for (int p0 = 0; p0 < kP && cnt < kK; p0 += 64) {
        int i = p0 + lane;
        float x = pb[i * 3 + 0], y = pb[i * 3 + 1], z = pb[i * 3 + 2];
        float d2 = dist2(x, y, z, cx, cy, cz);
        bool in = d2 <= R2;
        unsigned long long mask = __ballot(in);
        int rank = __popcll(mask & ((1ull << lane) - 1ull));
        if (in && cnt + rank < kK) {
            nb[(size_t)c * kK + cnt + rank] = (uint16_t)i;
        }
        cnt = min(cnt + (int)__popcll(mask), kK);
    }
    if (lane == 0) {
        cnt_arr[c] = cnt;
        batch_out[c] = (float)b;
    }
}

// ---------------------------------------------------------------------------
// Kernel 3: gather -> MLP (35->64->64->128, ReLU) -> masked max over K.
// One block (256 threads) per centroid. msg/h1/h2 staged in LDS; each thread
// holds its weight column in registers; LDS reads are same-address broadcast.
// ---------------------------------------------------------------------------
__global__ __launch_bounds__(256) void mlp_kernel(const float* __restrict__ pos,
                                                  const float* __restrict__ x,
                                                  const float* __restrict__ cent,
                                                  const uint16_t* __restrict__ nb,
                                                  const int* __restrict__ cnt_arr,
                                                  const float* __restrict__ W1,
                                                  const float* __restrict__ b1,
                                                  const float* __restrict__ W2,
                                                  const float* __restrict__ b2,
                                                  const float* __restrict__ W3,
                                                  const float* __restrict__ b3,
                                                  float* __restrict__ feat_out) {
    const int c = blockIdx.x;
    const int b = c >> 11;
    const int tid = threadIdx.x;

    __shared__ float msg[kK][36];     // 35 used, stride 36
    __shared__ float h1[kK][kH];
    __shared__ float h2[kK][kH];
    __shared__ float s_cent[3];
    __shared__ int s_nb[kK];
    __shared__ int s_cnt;
    __shared__ float red[2][kO];

    if (tid < kK) s_nb[tid] = nb[(size_t)c * kK + tid];
    if (tid == 0) s_cnt = cnt_arr[c];
    if (tid < 3) s_cent[tid] = cent[(size_t)c * 3 + tid];
    __syncthreads();
    const int cnt = s_cnt;

    // gather msg = [x_j (32) | pos_j - cent (3)]
    for (int u = tid; u < kK * 35; u += 256) {
        int k = u / 35, f = u - k * 35;
        float v = 0.0f;
        if (k < cnt) {
            int n = s_nb[k];
            if (f < 32) v = x[((size_t)b * kP + n) * kF + f];
            else        v = pos[((size_t)b * kP + n) * 3 + (f - 32)] - s_cent[f - 32];
        }
        msg[k][f] = v;
    }
    __syncthreads();

    // layer 1: 35 -> 64
    {
        int j = tid & 63, k0 = tid >> 6;  // k0 in [0,4)
        float w[35];
#pragma unroll
        for (int i = 0; i < 35; ++i) w[i] = W1[i * 64 + j];
        float bb = b1[j];
#pragma unroll
        for (int kk = 0; kk < 16; ++kk) {
            int k = k0 * 16 + kk;
            float acc = bb;
#pragma unroll
            for (int i = 0; i < 35; ++i) acc += msg[k][i] * w[i];
            h1[k][j] = fmaxf(acc, 0.0f);
        }
    }
    __syncthreads();

    // layer 2: 64 -> 64
    {
        int j = tid & 63, k0 = tid >> 6;
        float w[64];
#pragma unroll
        for (int i = 0; i < 64; ++i) w[i] = W2[i * 64 + j];
        float bb = b2[j];
#pragma unroll
        for (int kk = 0; kk < 16; ++kk) {
            int k = k0 * 16 + kk;
            float acc = bb;
#pragma unroll
            for (int i = 0; i < 64; ++i) acc += h1[k][i] * w[i];
            h2[k][j] = fmaxf(acc, 0.0f);
        }
    }
    __syncthreads();

    // layer 3: 64 -> 128, fused masked max over valid k
    {
        int j = tid & 127, k0 = tid >> 7;  // k0 in {0,1}
        float w[64];
#pragma unroll
        for (int i = 0; i < 64; ++i) w[i] = W3[i * 128 + j];
        float bb = b3[j];
        float best = -INFINITY;
        for (int kk = 0; kk < 32; ++kk) {
            int k = k0 * 32 + kk;      // wave-uniform bound
            if (k >= cnt) break;
            float acc = bb;
#pragma unroll
            for (int i = 0; i < 64; ++i) acc += h2[k][i] * w[i];
            best = fmaxf(best, fmaxf(acc, 0.0f));
        }
        red[k0][j] = best;
    }
    __syncthreads();

    if (tid < kO) {
        float o = fmaxf(red[0][tid], red[1][tid]);  // cnt>=1 -> red[0] valid
        feat_out[(size_t)c * kO + tid] = o;
    }
}

// ---------------------------------------------------------------------------
extern "C" void kernel_launch(void* const* d_in, const int* in_sizes, int n_in,
                              void* d_out, int out_size, void* d_ws, size_t ws_size,
                              hipStream_t stream) {
    const float* pos = (const float*)d_in[0];
    // d_in[1] = batch (unused; implied by layout)
    const float* x  = (const float*)d_in[2];
    const float* W1 = (const float*)d_in[3];
    const float* b1 = (const float*)d_in[4];
    const float* W2 = (const float*)d_in[5];
    const float* b2 = (const float*)d_in[6];
    const float* W3 = (const float*)d_in[7];
    const float* b3 = (const float*)d_in[8];

    float* out = (float*)d_out;
    float* cent_out  = out;                                   // [B*M, 3]
    float* feat_out  = out + (size_t)kB * kM * 3;             // [B*M, 128]
    float* batch_out = out + (size_t)kB * kM * (3 + kO);      // [B*M]

    char* ws = (char*)d_ws;
    int* cnt_arr   = (int*)ws;                                // B*M ints
    uint16_t* nbuf = (uint16_t*)(ws + (size_t)kB * kM * 4);   // B*M*K u16

    fps_kernel<<<kB, 512, 0, stream>>>(pos, cent_out);
    ball_kernel<<<(kB * kM) / 4, 256, 0, stream>>>(pos, cent_out, nbuf, cnt_arr, batch_out);
    mlp_kernel<<<kB * kM, 256, 0, stream>>>(pos, x, cent_out, nbuf, cnt_arr,
                                            W1, b1, W2, b2, W3, b3, feat_out);
}

// Round 6
// 3013.967 us; speedup vs baseline: 1.0686x; 1.0686x over previous
//
#include <hip/hip_runtime.h>
#include <stdint.h>
#include <math.h>

// Problem constants (from reference)
constexpr int kB = 8;      // clouds
constexpr int kP = 8192;   // points per cloud
constexpr int kF = 32;     // feature dim
constexpr int kM = 2048;   // centroids per cloud (P * 0.25)
constexpr int kK = 64;     // max neighbors
constexpr int kH = 64;     // hidden dim
constexpr int kO = 128;    // output dim

typedef float v2f __attribute__((ext_vector_type(2)));

// Exact-f32 squared distance matching numpy: square elementwise, then
// sequential sum ((dx2+dy2)+dz2). contract(off) forbids fma fusion so this
// matches numpy bit-for-bit regardless of -ffp-contract=fast default.
__device__ __forceinline__ float dist2(float ax, float ay, float az,
                                       float bx, float by, float bz) {
#pragma clang fp contract(off)
    float dx = ax - bx, dy = ay - by, dz = az - bz;
    return (dx * dx + dy * dy) + dz * dz;
}

// ---------------------------------------------------------------------------
// Kernel 1: farthest point sampling. One block (256 threads = 4 waves,
// 1 wave/SIMD) per cloud; 32 points per thread, packed as 16 float2 so the
// distance update uses v_pk_add/mul_f32 (IEEE-exact per slot, contract off,
// same association as numpy -> bit-identical).
// Per iter: packed dd update -> fmax tree -> descending locate (lowest idx
// on exact tie = numpy argmax first-occurrence) -> u64 key
// (dist_bits<<32 | ~idx) -> 6-step shfl_xor butterfly -> 4 LDS partials,
// 1 barrier, broadcast scan -> winner coords via broadcast LDS reads.
// No global stores in the loop: winner indices in LDS, writeout at end.
// ---------------------------------------------------------------------------
__global__ __launch_bounds__(256, 1) void fps_kernel(const float* __restrict__ pos,
                                                     float* __restrict__ cent_out) {
    const int b = blockIdx.x;
    const int tid = threadIdx.x;
    const float* pb = pos + (size_t)b * kP * 3;

    __shared__ float sxp[kP], syp[kP], szp[kP];   // SoA copy of this cloud
    __shared__ unsigned short widx[kM];           // winner index per iteration
    __shared__ unsigned long long part[2][4];     // ping-pong wave partials

    // load cloud into LDS (point i owned by thread i%256, slot i/256)
    v2f px2[16], py2[16], pz2[16], dd2[16];
#pragma unroll
    for (int q = 0; q < 32; ++q) {
        int i = tid + q * 256;
        float X = pb[i * 3 + 0];
        float Y = pb[i * 3 + 1];
        float Z = pb[i * 3 + 2];
        sxp[i] = X; syp[i] = Y; szp[i] = Z;
        if (q & 1) { px2[q >> 1].y = X; py2[q >> 1].y = Y; pz2[q >> 1].y = Z; }
        else       { px2[q >> 1].x = X; py2[q >> 1].x = Y; pz2[q >> 1].x = Z; }
    }
#pragma unroll
    for (int q = 0; q < 16; ++q) dd2[q] = (v2f){INFINITY, INFINITY};

    if (tid == 0) widx[0] = 0;
    __syncthreads();

    // first selected point: original index 0
    float lx = sxp[0], ly = syp[0], lz = szp[0];

    const int wave = tid >> 6, lane = tid & 63;

    for (int m = 1; m < kM; ++m) {
        // --- packed dd update (exact: pk mul/add, contract off) ---
        v2f lxv = {lx, lx}, lyv = {ly, ly}, lzv = {lz, lz};
#pragma unroll
        for (int q = 0; q < 16; ++q) {
#pragma clang fp contract(off)
            v2f dx = px2[q] - lxv;
            v2f dy = py2[q] - lyv;
            v2f dz = pz2[q] - lzv;
            v2f d2 = (dx * dx + dy * dy) + dz * dz;
            dd2[q].x = fminf(dd2[q].x, d2.x);
            dd2[q].y = fminf(dd2[q].y, d2.y);
        }

        // --- thread max (balanced fmax tree over 16 float2) ---
        v2f t0 = {fmaxf(dd2[0].x, dd2[0].y), fmaxf(dd2[1].x, dd2[1].y)};
        v2f t1 = {fmaxf(dd2[2].x, dd2[2].y), fmaxf(dd2[3].x, dd2[3].y)};
        v2f t2 = {fmaxf(dd2[4].x, dd2[4].y), fmaxf(dd2[5].x, dd2[5].y)};
        v2f t3 = {fmaxf(dd2[6].x, dd2[6].y), fmaxf(dd2[7].x, dd2[7].y)};
        v2f t4 = {fmaxf(dd2[8].x, dd2[8].y), fmaxf(dd2[9].x, dd2[9].y)};
        v2f t5 = {fmaxf(dd2[10].x, dd2[10].y), fmaxf(dd2[11].x, dd2[11].y)};
        v2f t6 = {fmaxf(dd2[12].x, dd2[12].y), fmaxf(dd2[13].x, dd2[13].y)};
        v2f t7 = {fmaxf(dd2[14].x, dd2[14].y), fmaxf(dd2[15].x, dd2[15].y)};
        float u0 = fmaxf(fmaxf(t0.x, t0.y), fmaxf(t1.x, t1.y));
        float u1 = fmaxf(fmaxf(t2.x, t2.y), fmaxf(t3.x, t3.y));
        float u2 = fmaxf(fmaxf(t4.x, t4.y), fmaxf(t5.x, t5.y));
        float u3 = fmaxf(fmaxf(t6.x, t6.y), fmaxf(t7.x, t7.y));
        float bv = fmaxf(fmaxf(u0, u1), fmaxf(u2, u3));

        // --- locate lowest owned slot with dd == bv (descending scan) ---
        int bq = 0;
#pragma unroll
        for (int s = 31; s >= 0; --s) {
            float v = (s & 1) ? dd2[s >> 1].y : dd2[s >> 1].x;
            bq = (v == bv) ? s : bq;
        }
        unsigned int bidx = (unsigned int)(tid + bq * 256);
        unsigned long long key =
            ((unsigned long long)__float_as_uint(bv) << 32) | (unsigned int)(~bidx);

        // --- wave butterfly max on u64 key ---
#pragma unroll
        for (int off = 32; off >= 1; off >>= 1) {
            unsigned long long ok = __shfl_xor(key, off, 64);
            if (ok > key) key = ok;
        }
        if (lane == 0) part[m & 1][wave] = key;
        __syncthreads();

        // --- block winner from 4 partials (broadcast reads) ---
        unsigned long long k = part[m & 1][0];
#pragma unroll
        for (int w = 1; w < 4; ++w) {
            unsigned long long o = part[m & 1][w];
            if (o > k) k = o;
        }
        unsigned int wi = ~(unsigned int)k;        // recover original index
        lx = sxp[wi]; ly = syp[wi]; lz = szp[wi];  // broadcast reads
        if (tid == 0) widx[m] = (unsigned short)wi;
        // ping-pong part[] + next barrier order the WAR hazard
    }
    __syncthreads();

    // cooperative centroid writeout (bit-exact copies of input coords)
#pragma unroll
    for (int q = 0; q < kM / 256; ++q) {
        int i = tid + q * 256;
        unsigned int wi = widx[i];
        size_t o = (size_t)(b * kM + i) * 3;
        cent_out[o + 0] = sxp[wi];
        cent_out[o + 1] = syp[wi];
        cent_out[o + 2] = szp[wi];
    }
}

// ---------------------------------------------------------------------------
// Kernel 2: radius ball query. One wave per centroid (4 waves / 256-thread
// block). Scan points in index order 64 at a time; ballot + prefix popcount
// assigns output slots -> lowest indices first, exactly like the reference's
// sort+take-K. Early exit once K neighbors found.
// ---------------------------------------------------------------------------
__global__ __launch_bounds__(256) void ball_kernel(const float* __restrict__ pos,
                                                   const float* __restrict__ cent,
                                                   uint16_t* __restrict__ nb,
                                                   int* __restrict__ cnt_arr,
                                                   float* __restrict__ batch_out) {
    const int wave = threadIdx.x >> 6, lane = threadIdx.x & 63;
    const int c = blockIdx.x * 4 + wave;
    const int b = c >> 11;  // c / kM
    const float R2 = (float)(0.2 * 0.2);  // same double->float rounding as reference

    float cx = cent[(size_t)c * 3 + 0];
    float cy = cent[(size_t)c * 3 + 1];
    float cz = cent[(size_t)c * 3 + 2];
    const float* pb = pos + (size_t)b * kP * 3;

    int cnt = 0;
    for (int p0 = 0; p0 < kP && cnt < kK; p0 += 64) {
        int i = p0 + lane;
        float x = pb[i * 3 + 0], y = pb[i * 3 + 1], z = pb[i * 3 + 2];
        float d2 = dist2(x, y, z, cx, cy, cz);
        bool in = d2 <= R2;
        unsigned long long mask = __ballot(in);
        int rank = __popcll(mask & ((1ull << lane) - 1ull));
        if (in && cnt + rank < kK) {
            nb[(size_t)c * kK + cnt + rank] = (uint16_t)i;
        }
        cnt = min(cnt + (int)__popcll(mask), kK);
    }
    if (lane == 0) {
        cnt_arr[c] = cnt;
        batch_out[c] = (float)b;
    }
}

// ---------------------------------------------------------------------------
// Kernel 3: gather -> MLP (35->64->64->128, ReLU) -> masked max over K.
// One block (256 threads) per centroid. msg/h1/h2 staged in LDS; each thread
// holds its weight column in registers; LDS reads are same-address broadcast.
// ---------------------------------------------------------------------------
__global__ __launch_bounds__(256) void mlp_kernel(const float* __restrict__ pos,
                                                  const float* __restrict__ x,
                                                  const float* __restrict__ cent,
                                                  const uint16_t* __restrict__ nb,
                                                  const int* __restrict__ cnt_arr,
                                                  const float* __restrict__ W1,
                                                  const float* __restrict__ b1,
                                                  const float* __restrict__ W2,
                                                  const float* __restrict__ b2,
                                                  const float* __restrict__ W3,
                                                  const float* __restrict__ b3,
                                                  float* __restrict__ feat_out) {
    const int c = blockIdx.x;
    const int b = c >> 11;
    const int tid = threadIdx.x;

    __shared__ float msg[kK][36];     // 35 used, stride 36
    __shared__ float h1[kK][kH];
    __shared__ float h2[kK][kH];
    __shared__ float s_cent[3];
    __shared__ int s_nb[kK];
    __shared__ int s_cnt;
    __shared__ float red[2][kO];

    if (tid < kK) s_nb[tid] = nb[(size_t)c * kK + tid];
    if (tid == 0) s_cnt = cnt_arr[c];
    if (tid < 3) s_cent[tid] = cent[(size_t)c * 3 + tid];
    __syncthreads();
    const int cnt = s_cnt;

    // gather msg = [x_j (32) | pos_j - cent (3)]
    for (int u = tid; u < kK * 35; u += 256) {
        int k = u / 35, f = u - k * 35;
        float v = 0.0f;
        if (k < cnt) {
            int n = s_nb[k];
            if (f < 32) v = x[((size_t)b * kP + n) * kF + f];
            else        v = pos[((size_t)b * kP + n) * 3 + (f - 32)] - s_cent[f - 32];
        }
        msg[k][f] = v;
    }
    __syncthreads();

    // layer 1: 35 -> 64
    {
        int j = tid & 63, k0 = tid >> 6;  // k0 in [0,4)
        float w[35];
#pragma unroll
        for (int i = 0; i < 35; ++i) w[i] = W1[i * 64 + j];
        float bb = b1[j];
#pragma unroll
        for (int kk = 0; kk < 16; ++kk) {
            int k = k0 * 16 + kk;
            float acc = bb;
#pragma unroll
            for (int i = 0; i < 35; ++i) acc += msg[k][i] * w[i];
            h1[k][j] = fmaxf(acc, 0.0f);
        }
    }
    __syncthreads();

    // layer 2: 64 -> 64
    {
        int j = tid & 63, k0 = tid >> 6;
        float w[64];
#pragma unroll
        for (int i = 0; i < 64; ++i) w[i] = W2[i * 64 + j];
        float bb = b2[j];
#pragma unroll
        for (int kk = 0; kk < 16; ++kk) {
            int k = k0 * 16 + kk;
            float acc = bb;
#pragma unroll
            for (int i = 0; i < 64; ++i) acc += h1[k][i] * w[i];
            h2[k][j] = fmaxf(acc, 0.0f);
        }
    }
    __syncthreads();

    // layer 3: 64 -> 128, fused masked max over valid k
    {
        int j = tid & 127, k0 = tid >> 7;  // k0 in {0,1}
        float w[64];
#pragma unroll
        for (int i = 0; i < 64; ++i) w[i] = W3[i * 128 + j];
        float bb = b3[j];
        float best = -INFINITY;
        for (int kk = 0; kk < 32; ++kk) {
            int k = k0 * 32 + kk;      // wave-uniform bound
            if (k >= cnt) break;
            float acc = bb;
#pragma unroll
            for (int i = 0; i < 64; ++i) acc += h2[k][i] * w[i];
            best = fmaxf(best, fmaxf(acc, 0.0f));
        }
        red[k0][j] = best;
    }
    __syncthreads();

    if (tid < kO) {
        float o = fmaxf(red[0][tid], red[1][tid]);  // cnt>=1 -> red[0] valid
        feat_out[(size_t)c * kO + tid] = o;
    }
}

// ---------------------------------------------------------------------------
extern "C" void kernel_launch(void* const* d_in, const int* in_sizes, int n_in,
                              void* d_out, int out_size, void* d_ws, size_t ws_size,
                              hipStream_t stream) {
    const float* pos = (const float*)d_in[0];
    // d_in[1] = batch (unused; implied by layout)
    const float* x  = (const float*)d_in[2];
    const float* W1 = (const float*)d_in[3];
    const float* b1 = (const float*)d_in[4];
    const float* W2 = (const float*)d_in[5];
    const float* b2 = (const float*)d_in[6];
    const float* W3 = (const float*)d_in[7];
    const float* b3 = (const float*)d_in[8];

    float* out = (float*)d_out;
    float* cent_out  = out;                                   // [B*M, 3]
    float* feat_out  = out + (size_t)kB * kM * 3;             // [B*M, 128]
    float* batch_out = out + (size_t)kB * kM * (3 + kO);      // [B*M]

    char* ws = (char*)d_ws;
    int* cnt_arr   = (int*)ws;                                // B*M ints
    uint16_t* nbuf = (uint16_t*)(ws + (size_t)kB * kM * 4);   // B*M*K u16

    fps_kernel<<<kB, 256, 0, stream>>>(pos, cent_out);
    ball_kernel<<<(kB * kM) / 4, 256, 0, stream>>>(pos, cent_out, nbuf, cnt_arr, batch_out);
    mlp_kernel<<<kB * kM, 256, 0, stream>>>(pos, x, cent_out, nbuf, cnt_arr,
                                            W1, b1, W2, b2, W3, b3, feat_out);
}

// Round 8
// 2792.426 us; speedup vs baseline: 1.1534x; 1.0793x over previous
//
#include <hip/hip_runtime.h>
#include <stdint.h>
#include <math.h>

// Problem constants (from reference)
constexpr int kB = 8;      // clouds
constexpr int kP = 8192;   // points per cloud
constexpr int kF = 32;     // feature dim
constexpr int kM = 2048;   // centroids per cloud (P * 0.25)
constexpr int kK = 64;     // max neighbors
constexpr int kH = 64;     // hidden dim
constexpr int kO = 128;    // output dim

typedef float v2f __attribute__((ext_vector_type(2)));

// Exact-f32 squared distance matching numpy: square elementwise, then
// sequential sum ((dx2+dy2)+dz2). contract(off) forbids fma fusion so this
// matches numpy bit-for-bit regardless of -ffp-contract=fast default.
__device__ __forceinline__ float dist2(float ax, float ay, float az,
                                       float bx, float by, float bz) {
#pragma clang fp contract(off)
    float dx = ax - bx, dy = ay - by, dz = az - bz;
    return (dx * dx + dy * dy) + dz * dz;
}

// One DPP step of a u64 (hi,lo) max-reduce. CTRL must be an immediate ->
// template parameter. bound_ctrl=true: invalid source lanes read 0, and
// (0,0) never wins because all real keys have hi >= 0 with klo = ~idx != 0.
template <int CTRL>
__device__ __forceinline__ void dpp_max_step(unsigned int& khi, unsigned int& klo) {
    unsigned int ohi = (unsigned int)__builtin_amdgcn_update_dpp(
        0, (int)khi, CTRL, 0xf, 0xf, true);
    unsigned int olo = (unsigned int)__builtin_amdgcn_update_dpp(
        0, (int)klo, CTRL, 0xf, 0xf, true);
    bool take = (ohi > khi) || (ohi == khi && olo > klo);
    khi = take ? ohi : khi;
    klo = take ? olo : klo;
}

// ---------------------------------------------------------------------------
// Kernel 1: farthest point sampling. One block (256 threads = 4 waves,
// 1 wave/SIMD) per cloud; 32 points per thread packed as 16 float2
// (v_pk_* update, IEEE-exact per slot, contract off -> bit-identical).
// Per iter: packed dd update -> pk-max tree -> grouped locate (lowest idx
// on exact tie = numpy argmax first-occurrence) -> u64 key
// (dist_bits<<32 | ~idx) -> 6-step DPP u64 max-reduce in the VALU pipe
// (row_shr 1/2/4/8 + row_bcast 15/31; lane 63 holds the wave max — the
// rocPRIM wave64 sequence, bit-exact-validated on this HW in r5) ->
// 4 LDS partials, 1 barrier, broadcast scan -> winner coords via LDS.
// No global stores in the loop: winner indices in LDS, writeout at end.
// ---------------------------------------------------------------------------
__global__ __launch_bounds__(256, 1) void fps_kernel(const float* __restrict__ pos,
                                                     float* __restrict__ cent_out) {
    const int b = blockIdx.x;
    const int tid = threadIdx.x;
    const float* pb = pos + (size_t)b * kP * 3;

    __shared__ float sxp[kP], syp[kP], szp[kP];   // SoA copy of this cloud
    __shared__ unsigned short widx[kM];           // winner index per iteration
    __shared__ unsigned long long part[2][4];     // ping-pong wave partials

    // load cloud into LDS (point i owned by thread i%256, slot i/256)
    v2f px2[16], py2[16], pz2[16], dd2[16];
#pragma unroll
    for (int q = 0; q < 32; ++q) {
        int i = tid + q * 256;
        float X = pb[i * 3 + 0];
        float Y = pb[i * 3 + 1];
        float Z = pb[i * 3 + 2];
        sxp[i] = X; syp[i] = Y; szp[i] = Z;
        if (q & 1) { px2[q >> 1].y = X; py2[q >> 1].y = Y; pz2[q >> 1].y = Z; }
        else       { px2[q >> 1].x = X; py2[q >> 1].x = Y; pz2[q >> 1].x = Z; }
    }
#pragma unroll
    for (int q = 0; q < 16; ++q) dd2[q] = (v2f){INFINITY, INFINITY};

    if (tid == 0) widx[0] = 0;
    __syncthreads();

    // first selected point: original index 0
    float lx = sxp[0], ly = syp[0], lz = szp[0];

    const int wave = tid >> 6, lane = tid & 63;

    for (int m = 1; m < kM; ++m) {
        // --- packed dd update (exact: pk mul/add, contract off) ---
        v2f lxv = {lx, lx}, lyv = {ly, ly}, lzv = {lz, lz};
#pragma unroll
        for (int q = 0; q < 16; ++q) {
#pragma clang fp contract(off)
            v2f dx = px2[q] - lxv;
            v2f dy = py2[q] - lyv;
            v2f dz = pz2[q] - lzv;
            v2f d2 = (dx * dx + dy * dy) + dz * dz;
            dd2[q].x = fminf(dd2[q].x, d2.x);
            dd2[q].y = fminf(dd2[q].y, d2.y);
        }

        // --- thread max (balanced pairwise-max tree over 16 float2) ---
        v2f t0 = {fmaxf(dd2[0].x, dd2[0].y), fmaxf(dd2[1].x, dd2[1].y)};
        v2f t1 = {fmaxf(dd2[2].x, dd2[2].y), fmaxf(dd2[3].x, dd2[3].y)};
        v2f t2 = {fmaxf(dd2[4].x, dd2[4].y), fmaxf(dd2[5].x, dd2[5].y)};
        v2f t3 = {fmaxf(dd2[6].x, dd2[6].y), fmaxf(dd2[7].x, dd2[7].y)};
        v2f t4 = {fmaxf(dd2[8].x, dd2[8].y), fmaxf(dd2[9].x, dd2[9].y)};
        v2f t5 = {fmaxf(dd2[10].x, dd2[10].y), fmaxf(dd2[11].x, dd2[11].y)};
        v2f t6 = {fmaxf(dd2[12].x, dd2[12].y), fmaxf(dd2[13].x, dd2[13].y)};
        v2f t7 = {fmaxf(dd2[14].x, dd2[14].y), fmaxf(dd2[15].x, dd2[15].y)};
        float u0 = fmaxf(fmaxf(t0.x, t0.y), fmaxf(t1.x, t1.y));
        float u1 = fmaxf(fmaxf(t2.x, t2.y), fmaxf(t3.x, t3.y));
        float u2 = fmaxf(fmaxf(t4.x, t4.y), fmaxf(t5.x, t5.y));
        float u3 = fmaxf(fmaxf(t6.x, t6.y), fmaxf(t7.x, t7.y));
        float bv = fmaxf(fmaxf(u0, u1), fmaxf(u2, u3));

        // --- grouped locate: lowest owned slot with dd == bv ---
        // 4 independent 8-deep chains (ILP) + 3-select combine.
        int lqs[4];
#pragma unroll
        for (int g = 0; g < 4; ++g) {
            int t = 64;
#pragma unroll
            for (int s = 7; s >= 0; --s) {
                int sl = g * 8 + s;
                float v = (sl & 1) ? dd2[sl >> 1].y : dd2[sl >> 1].x;
                t = (v == bv) ? sl : t;
            }
            lqs[g] = t;
        }
        int bq = lqs[3];
        bq = (lqs[2] < 64) ? lqs[2] : bq;
        bq = (lqs[1] < 64) ? lqs[1] : bq;
        bq = (lqs[0] < 64) ? lqs[0] : bq;

        unsigned int bidx = (unsigned int)(tid + bq * 256);
        unsigned int khi = __float_as_uint(bv);
        unsigned int klo = (unsigned int)(~bidx);

        // --- wave u64 max-reduce via DPP (VALU pipe; lane 63 = wave max) ---
        dpp_max_step<0x111>(khi, klo);   // row_shr:1
        dpp_max_step<0x112>(khi, klo);   // row_shr:2
        dpp_max_step<0x114>(khi, klo);   // row_shr:4
        dpp_max_step<0x118>(khi, klo);   // row_shr:8
        dpp_max_step<0x142>(khi, klo);   // row_bcast:15
        dpp_max_step<0x143>(khi, klo);   // row_bcast:31
        if (lane == 63)
            part[m & 1][wave] = ((unsigned long long)khi << 32) | klo;
        __syncthreads();

        // --- block winner from 4 partials (broadcast reads) ---
        unsigned long long k = part[m & 1][0];
#pragma unroll
        for (int w = 1; w < 4; ++w) {
            unsigned long long o = part[m & 1][w];
            if (o > k) k = o;
        }
        unsigned int wi = ~(unsigned int)k;        // recover original index
        lx = sxp[wi]; ly = syp[wi]; lz = szp[wi];  // broadcast reads
        if (tid == 0) widx[m] = (unsigned short)wi;
        // ping-pong part[] + next barrier order the WAR hazard
    }
    __syncthreads();

    // cooperative centroid writeout (bit-exact copies of input coords)
#pragma unroll
    for (int q = 0; q < kM / 256; ++q) {
        int i = tid + q * 256;
        unsigned int wi = widx[i];
        size_t o = (size_t)(b * kM + i) * 3;
        cent_out[o + 0] = sxp[wi];
        cent_out[o + 1] = syp[wi];
        cent_out[o + 2] = szp[wi];
    }
}

// ---------------------------------------------------------------------------
// Kernel 2: radius ball query. One wave per centroid (4 waves / 256-thread
// block). Scan points in index order 64 at a time; ballot + prefix popcount
// assigns output slots -> lowest indices first, exactly like the reference's
// sort+take-K. Early exit once K neighbors found.
// ---------------------------------------------------------------------------
__global__ __launch_bounds__(256) void ball_kernel(const float* __restrict__ pos,
                                                   const float* __restrict__ cent,
                                                   uint16_t* __restrict__ nb,
                                                   int* __restrict__ cnt_arr,
                                                   float* __restrict__ batch_out) {
    const int wave = threadIdx.x >> 6, lane = threadIdx.x & 63;
    const int c = blockIdx.x * 4 + wave;
    const int b = c >> 11;  // c / kM
    const float R2 = (float)(0.2 * 0.2);  // same double->float rounding as reference

    float cx = cent[(size_t)c * 3 + 0];
    float cy = cent[(size_t)c * 3 + 1];
    float cz = cent[(size_t)c * 3 + 2];
    const float* pb = pos + (size_t)b * kP * 3;

    int cnt = 0;
    for (int p0 = 0; p0 < kP && cnt < kK; p0 += 64) {
        int i = p0 + lane;
        float x = pb[i * 3 + 0], y = pb[i * 3 + 1], z = pb[i * 3 + 2];
        float d2 = dist2(x, y, z, cx, cy, cz);
        bool in = d2 <= R2;
        unsigned long long mask = __ballot(in);
        int rank = __popcll(mask & ((1ull << lane) - 1ull));
        if (in && cnt + rank < kK) {
            nb[(size_t)c * kK + cnt + rank] = (uint16_t)i;
        }
        cnt = min(cnt + (int)__popcll(mask), kK);
    }
    if (lane == 0) {
        cnt_arr[c] = cnt;
        batch_out[c] = (float)b;
    }
}

// ---------------------------------------------------------------------------
// Kernel 3: gather -> MLP (35->64->64->128, ReLU) -> masked max over K.
// One block (256 threads) per centroid. msg/h1/h2 staged in LDS; each thread
// holds its weight column in registers; LDS reads are same-address broadcast.
// ---------------------------------------------------------------------------
__global__ __launch_bounds__(256) void mlp_kernel(const float* __restrict__ pos,
                                                  const float* __restrict__ x,
                                                  const float* __restrict__ cent,
                                                  const uint16_t* __restrict__ nb,
                                                  const int* __restrict__ cnt_arr,
                                                  const float* __restrict__ W1,
                                                  const float* __restrict__ b1,
                                                  const float* __restrict__ W2,
                                                  const float* __restrict__ b2,
                                                  const float* __restrict__ W3,
                                                  const float* __restrict__ b3,
                                                  float* __restrict__ feat_out) {
    const int c = blockIdx.x;
    const int b = c >> 11;
    const int tid = threadIdx.x;

    __shared__ float msg[kK][36];     // 35 used, stride 36
    __shared__ float h1[kK][kH];
    __shared__ float h2[kK][kH];
    __shared__ float s_cent[3];
    __shared__ int s_nb[kK];
    __shared__ int s_cnt;
    __shared__ float red[2][kO];

    if (tid < kK) s_nb[tid] = nb[(size_t)c * kK + tid];
    if (tid == 0) s_cnt = cnt_arr[c];
    if (tid < 3) s_cent[tid] = cent[(size_t)c * 3 + tid];
    __syncthreads();
    const int cnt = s_cnt;

    // gather msg = [x_j (32) | pos_j - cent (3)]
    for (int u = tid; u < kK * 35; u += 256) {
        int k = u / 35, f = u - k * 35;
        float v = 0.0f;
        if (k < cnt) {
            int n = s_nb[k];
            if (f < 32) v = x[((size_t)b * kP + n) * kF + f];
            else        v = pos[((size_t)b * kP + n) * 3 + (f - 32)] - s_cent[f - 32];
        }
        msg[k][f] = v;
    }
    __syncthreads();

    // layer 1: 35 -> 64
    {
        int j = tid & 63, k0 = tid >> 6;  // k0 in [0,4)
        float w[35];
#pragma unroll
        for (int i = 0; i < 35; ++i) w[i] = W1[i * 64 + j];
        float bb = b1[j];
#pragma unroll
        for (int kk = 0; kk < 16; ++kk) {
            int k = k0 * 16 + kk;
            float acc = bb;
#pragma unroll
            for (int i = 0; i < 35; ++i) acc += msg[k][i] * w[i];
            h1[k][j] = fmaxf(acc, 0.0f);
        }
    }
    __syncthreads();

    // layer 2: 64 -> 64
    {
        int j = tid & 63, k0 = tid >> 6;
        float w[64];
#pragma unroll
        for (int i = 0; i < 64; ++i) w[i] = W2[i * 64 + j];
        float bb = b2[j];
#pragma unroll
        for (int kk = 0; kk < 16; ++kk) {
            int k = k0 * 16 + kk;
            float acc = bb;
#pragma unroll
            for (int i = 0; i < 64; ++i) acc += h1[k][i] * w[i];
            h2[k][j] = fmaxf(acc, 0.0f);
        }
    }
    __syncthreads();

    // layer 3: 64 -> 128, fused masked max over valid k
    {
        int j = tid & 127, k0 = tid >> 7;  // k0 in {0,1}
        float w[64];
#pragma unroll
        for (int i = 0; i < 64; ++i) w[i] = W3[i * 128 + j];
        float bb = b3[j];
        float best = -INFINITY;
        for (int kk = 0; kk < 32; ++kk) {
            int k = k0 * 32 + kk;      // wave-uniform bound
            if (k >= cnt) break;
            float acc = bb;
#pragma unroll
            for (int i = 0; i < 64; ++i) acc += h2[k][i] * w[i];
            best = fmaxf(best, fmaxf(acc, 0.0f));
        }
        red[k0][j] = best;
    }
    __syncthreads();

    if (tid < kO) {
        float o = fmaxf(red[0][tid], red[1][tid]);  // cnt>=1 -> red[0] valid
        feat_out[(size_t)c * kO + tid] = o;
    }
}

// ---------------------------------------------------------------------------
extern "C" void kernel_launch(void* const* d_in, const int* in_sizes, int n_in,
                              void* d_out, int out_size, void* d_ws, size_t ws_size,
                              hipStream_t stream) {
    const float* pos = (const float*)d_in[0];
    // d_in[1] = batch (unused; implied by layout)
    const float* x  = (const float*)d_in[2];
    const float* W1 = (const float*)d_in[3];
    const float* b1 = (const float*)d_in[4];
    const float* W2 = (const float*)d_in[5];
    const float* b2 = (const float*)d_in[6];
    const float* W3 = (const float*)d_in[7];
    const float* b3 = (const float*)d_in[8];

    float* out = (float*)d_out;
    float* cent_out  = out;                                   // [B*M, 3]
    float* feat_out  = out + (size_t)kB * kM * 3;             // [B*M, 128]
    float* batch_out = out + (size_t)kB * kM * (3 + kO);      // [B*M]

    char* ws = (char*)d_ws;
    int* cnt_arr   = (int*)ws;                                // B*M ints
    uint16_t* nbuf = (uint16_t*)(ws + (size_t)kB * kM * 4);   // B*M*K u16

    fps_kernel<<<kB, 256, 0, stream>>>(pos, cent_out);
    ball_kernel<<<(kB * kM) / 4, 256, 0, stream>>>(pos, cent_out, nbuf, cnt_arr, batch_out);
    mlp_kernel<<<kB * kM, 256, 0, stream>>>(pos, x, cent_out, nbuf, cnt_arr,
                                            W1, b1, W2, b2, W3, b3, feat_out);
}

// Round 9
// 2528.656 us; speedup vs baseline: 1.2737x; 1.1043x over previous
//
#include <hip/hip_runtime.h>
#include <stdint.h>
#include <math.h>

// Problem constants (from reference)
constexpr int kB = 8;      // clouds
constexpr int kP = 8192;   // points per cloud
constexpr int kF = 32;     // feature dim
constexpr int kM = 2048;   // centroids per cloud (P * 0.25)
constexpr int kK = 64;     // max neighbors
constexpr int kH = 64;     // hidden dim
constexpr int kO = 128;    // output dim

typedef float v2f __attribute__((ext_vector_type(2)));

// Exact-f32 squared distance matching numpy: square elementwise, then
// sequential sum ((dx2+dy2)+dz2). contract(off) forbids fma fusion so this
// matches numpy bit-for-bit regardless of -ffp-contract=fast default.
__device__ __forceinline__ float dist2(float ax, float ay, float az,
                                       float bx, float by, float bz) {
#pragma clang fp contract(off)
    float dx = ax - bx, dy = ay - by, dz = az - bz;
    return (dx * dx + dy * dy) + dz * dz;
}

// One DPP step of a u64 (hi,lo) max-reduce. CTRL must be an immediate ->
// template parameter. bound_ctrl=true: invalid source lanes read 0, and
// (0,0) never wins because all real keys have klo = ~idx != 0.
template <int CTRL>
__device__ __forceinline__ void dpp_max_step(unsigned int& khi, unsigned int& klo) {
    unsigned int ohi = (unsigned int)__builtin_amdgcn_update_dpp(
        0, (int)khi, CTRL, 0xf, 0xf, true);
    unsigned int olo = (unsigned int)__builtin_amdgcn_update_dpp(
        0, (int)klo, CTRL, 0xf, 0xf, true);
    bool take = (ohi > khi) || (ohi == khi && olo > klo);
    khi = take ? ohi : khi;
    klo = take ? olo : klo;
}

// Zero the progress flags (d_ws is poisoned 0xAA before every launch).
__global__ void init_kernel(int* __restrict__ prog) {
    if (threadIdx.x < 128) prog[threadIdx.x] = 0;
}

// ---------------------------------------------------------------------------
// Mega-kernel: producer/consumer overlap.
//  blocks 0..7       : FPS for cloud b (r8-proven math, bit-exact). Publishes
//                      each centroid to `stage` (agent-scope atomic stores)
//                      and a progress counter (release) every 32 iterations.
//  blocks 8..8+16383 : one centroid each, cloud-rotated (b = i&7) so resident
//                      blocks unlock at 8x the per-cloud fps rate. Spin on
//                      prog[b] (lane-0 poll + s_sleep), read cent via atomic
//                      loads (XCD-L2 coherence), then ball query (wave 0,
//                      LDS-local) + gather + MLP + masked max.
// Static LDS padded to ~84 KB -> 1 block/CU: consumer blocks can never share
// a CU with an FPS block (protects the fps serial chain's SIMD issue).
// ---------------------------------------------------------------------------
__global__ __launch_bounds__(256, 1) void mega_kernel(
    const float* __restrict__ pos, const float* __restrict__ x,
    const float* __restrict__ W1, const float* __restrict__ b1,
    const float* __restrict__ W2, const float* __restrict__ b2,
    const float* __restrict__ W3, const float* __restrict__ b3,
    unsigned int* __restrict__ stage, int* __restrict__ prog,
    float* __restrict__ cent_out, float* __restrict__ feat_out,
    float* __restrict__ batch_out) {
    __shared__ float msg[kK][36];     // 35 used, stride 36
    __shared__ float h1[kK][kH];
    __shared__ float h2[kK][kH];
    __shared__ float red[2][kO];
    __shared__ int s_nb[kK];
    __shared__ float s_cent[3];
    __shared__ int s_cnt;
    __shared__ unsigned long long part[2][4];   // fps ping-pong partials
    __shared__ char occ_pad[40960];             // force 1 block/CU
    if (blockIdx.x == 0x7fffffffu)              // never true; keeps occ_pad live
        ((volatile char*)occ_pad)[threadIdx.x] = 1;

    const int tid = threadIdx.x;
    const int wave = tid >> 6, lane = tid & 63;

    if (blockIdx.x < (unsigned)kB) {
        // ======================= FPS role =======================
        const int b = blockIdx.x;
        const float* pb = pos + (size_t)b * kP * 3;

        v2f px2[16], py2[16], pz2[16], dd2[16];
#pragma unroll
        for (int q = 0; q < 32; ++q) {
            int i = tid + q * 256;
            float X = pb[i * 3 + 0];
            float Y = pb[i * 3 + 1];
            float Z = pb[i * 3 + 2];
            if (q & 1) { px2[q >> 1].y = X; py2[q >> 1].y = Y; pz2[q >> 1].y = Z; }
            else       { px2[q >> 1].x = X; py2[q >> 1].x = Y; pz2[q >> 1].x = Z; }
        }
#pragma unroll
        for (int q = 0; q < 16; ++q) dd2[q] = (v2f){INFINITY, INFINITY};

        // first selected point: original index 0
        float lx = pb[0], ly = pb[1], lz = pb[2];
        if (tid == 0) {
            size_t o = (size_t)(b * kM) * 3;
            cent_out[o + 0] = lx; cent_out[o + 1] = ly; cent_out[o + 2] = lz;
            __hip_atomic_store(&stage[o + 0], __float_as_uint(lx),
                               __ATOMIC_RELAXED, __HIP_MEMORY_SCOPE_AGENT);
            __hip_atomic_store(&stage[o + 1], __float_as_uint(ly),
                               __ATOMIC_RELAXED, __HIP_MEMORY_SCOPE_AGENT);
            __hip_atomic_store(&stage[o + 2], __float_as_uint(lz),
                               __ATOMIC_RELAXED, __HIP_MEMORY_SCOPE_AGENT);
            __hip_atomic_store(&prog[b * 16], 1,
                               __ATOMIC_RELEASE, __HIP_MEMORY_SCOPE_AGENT);
        }

        for (int m = 1; m < kM; ++m) {
            // --- packed dd update (exact: pk mul/add, contract off) ---
            v2f lxv = {lx, lx}, lyv = {ly, ly}, lzv = {lz, lz};
#pragma unroll
            for (int q = 0; q < 16; ++q) {
#pragma clang fp contract(off)
                v2f dx = px2[q] - lxv;
                v2f dy = py2[q] - lyv;
                v2f dz = pz2[q] - lzv;
                v2f d2 = (dx * dx + dy * dy) + dz * dz;
                dd2[q].x = fminf(dd2[q].x, d2.x);
                dd2[q].y = fminf(dd2[q].y, d2.y);
            }

            // --- thread max (balanced pairwise-max tree over 16 float2) ---
            v2f t0 = {fmaxf(dd2[0].x, dd2[0].y), fmaxf(dd2[1].x, dd2[1].y)};
            v2f t1 = {fmaxf(dd2[2].x, dd2[2].y), fmaxf(dd2[3].x, dd2[3].y)};
            v2f t2 = {fmaxf(dd2[4].x, dd2[4].y), fmaxf(dd2[5].x, dd2[5].y)};
            v2f t3 = {fmaxf(dd2[6].x, dd2[6].y), fmaxf(dd2[7].x, dd2[7].y)};
            v2f t4 = {fmaxf(dd2[8].x, dd2[8].y), fmaxf(dd2[9].x, dd2[9].y)};
            v2f t5 = {fmaxf(dd2[10].x, dd2[10].y), fmaxf(dd2[11].x, dd2[11].y)};
            v2f t6 = {fmaxf(dd2[12].x, dd2[12].y), fmaxf(dd2[13].x, dd2[13].y)};
            v2f t7 = {fmaxf(dd2[14].x, dd2[14].y), fmaxf(dd2[15].x, dd2[15].y)};
            float u0 = fmaxf(fmaxf(t0.x, t0.y), fmaxf(t1.x, t1.y));
            float u1 = fmaxf(fmaxf(t2.x, t2.y), fmaxf(t3.x, t3.y));
            float u2 = fmaxf(fmaxf(t4.x, t4.y), fmaxf(t5.x, t5.y));
            float u3 = fmaxf(fmaxf(t6.x, t6.y), fmaxf(t7.x, t7.y));
            float bv = fmaxf(fmaxf(u0, u1), fmaxf(u2, u3));

            // --- grouped locate: lowest owned slot with dd == bv ---
            int lqs[4];
#pragma unroll
            for (int g = 0; g < 4; ++g) {
                int t = 64;
#pragma unroll
                for (int s = 7; s >= 0; --s) {
                    int sl = g * 8 + s;
                    float v = (sl & 1) ? dd2[sl >> 1].y : dd2[sl >> 1].x;
                    t = (v == bv) ? sl : t;
                }
                lqs[g] = t;
            }
            int bq = lqs[3];
            bq = (lqs[2] < 64) ? lqs[2] : bq;
            bq = (lqs[1] < 64) ? lqs[1] : bq;
            bq = (lqs[0] < 64) ? lqs[0] : bq;

            unsigned int bidx = (unsigned int)(tid + bq * 256);
            unsigned int khi = __float_as_uint(bv);
            unsigned int klo = (unsigned int)(~bidx);

            // --- wave u64 max-reduce via DPP (lane 63 = wave max) ---
            dpp_max_step<0x111>(khi, klo);   // row_shr:1
            dpp_max_step<0x112>(khi, klo);   // row_shr:2
            dpp_max_step<0x114>(khi, klo);   // row_shr:4
            dpp_max_step<0x118>(khi, klo);   // row_shr:8
            dpp_max_step<0x142>(khi, klo);   // row_bcast:15
            dpp_max_step<0x143>(khi, klo);   // row_bcast:31
            if (lane == 63)
                part[m & 1][wave] = ((unsigned long long)khi << 32) | klo;
            __syncthreads();

            // --- block winner from 4 partials (broadcast reads) ---
            unsigned long long k = part[m & 1][0];
#pragma unroll
            for (int w = 1; w < 4; ++w) {
                unsigned long long o = part[m & 1][w];
                if (o > k) k = o;
            }
            unsigned int wi = ~(unsigned int)k;   // original index
            // winner coords from global pos (read-only, L2-hot)
            lx = pb[wi * 3 + 0]; ly = pb[wi * 3 + 1]; lz = pb[wi * 3 + 2];

            if (tid == 0) {
                size_t o = (size_t)(b * kM + m) * 3;
                cent_out[o + 0] = lx; cent_out[o + 1] = ly; cent_out[o + 2] = lz;
                __hip_atomic_store(&stage[o + 0], __float_as_uint(lx),
                                   __ATOMIC_RELAXED, __HIP_MEMORY_SCOPE_AGENT);
                __hip_atomic_store(&stage[o + 1], __float_as_uint(ly),
                                   __ATOMIC_RELAXED, __HIP_MEMORY_SCOPE_AGENT);
                __hip_atomic_store(&stage[o + 2], __float_as_uint(lz),
                                   __ATOMIC_RELAXED, __HIP_MEMORY_SCOPE_AGENT);
                if ((m & 31) == 31)
                    __hip_atomic_store(&prog[b * 16], m + 1,
                                       __ATOMIC_RELEASE, __HIP_MEMORY_SCOPE_AGENT);
            }
            // ping-pong part[] + next barrier order the WAR hazard
        }
        return;
    }

    // ======================= consumer role =======================
    const int i = (int)blockIdx.x - kB;
    const int b = i & 7;          // cloud-rotated dispatch
    const int cl = i >> 3;        // centroid index within cloud
    const int c = b * kM + cl;    // global centroid id

    // wait until fps has published this centroid
    if (tid == 0) {
        while (__hip_atomic_load(&prog[b * 16], __ATOMIC_ACQUIRE,
                                 __HIP_MEMORY_SCOPE_AGENT) < cl + 1)
            __builtin_amdgcn_s_sleep(16);
    }
    __syncthreads();

    if (tid < 3) {
        unsigned int u = __hip_atomic_load(&stage[(size_t)c * 3 + tid],
                                           __ATOMIC_RELAXED, __HIP_MEMORY_SCOPE_AGENT);
        s_cent[tid] = __uint_as_float(u);
    }
    __syncthreads();

    // --- ball query (wave 0): ballot + prefix popcount, lowest indices
    // first (== reference sort+take-K), early exit at K ---
    if (wave == 0) {
        const float R2 = (float)(0.2 * 0.2);
        float cx = s_cent[0], cy = s_cent[1], cz = s_cent[2];
        const float* pb = pos + (size_t)b * kP * 3;
        int cnt = 0;
        for (int p0 = 0; p0 < kP && cnt < kK; p0 += 64) {
            int idx = p0 + lane;
            float X = pb[idx * 3 + 0], Y = pb[idx * 3 + 1], Z = pb[idx * 3 + 2];
            float d2 = dist2(X, Y, Z, cx, cy, cz);
            bool in = d2 <= R2;
            unsigned long long mask = __ballot(in);
            int rank = __popcll(mask & ((1ull << lane) - 1ull));
            if (in && cnt + rank < kK) s_nb[cnt + rank] = idx;
            cnt = min(cnt + (int)__popcll(mask), kK);
        }
        if (lane == 0) { s_cnt = cnt; batch_out[c] = (float)b; }
    }
    __syncthreads();
    const int cnt = s_cnt;

    // --- gather msg = [x_j (32) | pos_j - cent (3)] ---
    for (int u = tid; u < kK * 35; u += 256) {
        int k = u / 35, f = u - k * 35;
        float v = 0.0f;
        if (k < cnt) {
            int n = s_nb[k];
            if (f < 32) v = x[((size_t)b * kP + n) * kF + f];
            else        v = pos[((size_t)b * kP + n) * 3 + (f - 32)] - s_cent[f - 32];
        }
        msg[k][f] = v;
    }
    __syncthreads();

    // layer 1: 35 -> 64
    {
        int j = tid & 63, k0 = tid >> 6;
        float w[35];
#pragma unroll
        for (int q = 0; q < 35; ++q) w[q] = W1[q * 64 + j];
        float bb = b1[j];
#pragma unroll
        for (int kk = 0; kk < 16; ++kk) {
            int k = k0 * 16 + kk;
            float acc = bb;
#pragma unroll
            for (int q = 0; q < 35; ++q) acc += msg[k][q] * w[q];
            h1[k][j] = fmaxf(acc, 0.0f);
        }
    }
    __syncthreads();

    // layer 2: 64 -> 64
    {
        int j = tid & 63, k0 = tid >> 6;
        float w[64];
#pragma unroll
        for (int q = 0; q < 64; ++q) w[q] = W2[q * 64 + j];
        float bb = b2[j];
#pragma unroll
        for (int kk = 0; kk < 16; ++kk) {
            int k = k0 * 16 + kk;
            float acc = bb;
#pragma unroll
            for (int q = 0; q < 64; ++q) acc += h1[k][q] * w[q];
            h2[k][j] = fmaxf(acc, 0.0f);
        }
    }
    __syncthreads();

    // layer 3: 64 -> 128, fused masked max over valid k
    {
        int j = tid & 127, k0 = tid >> 7;
        float w[64];
#pragma unroll
        for (int q = 0; q < 64; ++q) w[q] = W3[q * 128 + j];
        float bb = b3[j];
        float best = -INFINITY;
        for (int kk = 0; kk < 32; ++kk) {
            int k = k0 * 32 + kk;      // wave-uniform bound
            if (k >= cnt) break;
            float acc = bb;
#pragma unroll
            for (int q = 0; q < 64; ++q) acc += h2[k][q] * w[q];
            best = fmaxf(best, fmaxf(acc, 0.0f));
        }
        red[k0][j] = best;
    }
    __syncthreads();

    if (tid < kO) {
        float o = fmaxf(red[0][tid], red[1][tid]);   // cnt>=1 -> red[0] valid
        feat_out[(size_t)c * kO + tid] = o;
    }
}

// ---------------------------------------------------------------------------
extern "C" void kernel_launch(void* const* d_in, const int* in_sizes, int n_in,
                              void* d_out, int out_size, void* d_ws, size_t ws_size,
                              hipStream_t stream) {
    const float* pos = (const float*)d_in[0];
    // d_in[1] = batch (unused; implied by layout)
    const float* x  = (const float*)d_in[2];
    const float* W1 = (const float*)d_in[3];
    const float* b1 = (const float*)d_in[4];
    const float* W2 = (const float*)d_in[5];
    const float* b2 = (const float*)d_in[6];
    const float* W3 = (const float*)d_in[7];
    const float* b3 = (const float*)d_in[8];

    float* out = (float*)d_out;
    float* cent_out  = out;                                   // [B*M, 3]
    float* feat_out  = out + (size_t)kB * kM * 3;             // [B*M, 128]
    float* batch_out = out + (size_t)kB * kM * (3 + kO);      // [B*M]

    char* ws = (char*)d_ws;
    int* prog           = (int*)ws;                           // 128 ints (strided)
    unsigned int* stage = (unsigned int*)(ws + 512);          // B*M*3 uints

    init_kernel<<<1, 128, 0, stream>>>(prog);
    mega_kernel<<<kB + kB * kM, 256, 0, stream>>>(
        pos, x, W1, b1, W2, b2, W3, b3, stage, prog,
        cent_out, feat_out, batch_out);
}

// Round 10
// 2525.459 us; speedup vs baseline: 1.2753x; 1.0013x over previous
//
#include <hip/hip_runtime.h>
#include <stdint.h>
#include <math.h>

// Problem constants (from reference)
constexpr int kB = 8;      // clouds
constexpr int kP = 8192;   // points per cloud
constexpr int kF = 32;     // feature dim
constexpr int kM = 2048;   // centroids per cloud (P * 0.25)
constexpr int kK = 64;     // max neighbors
constexpr int kH = 64;     // hidden dim
constexpr int kO = 128;    // output dim

typedef float v2f __attribute__((ext_vector_type(2)));

// Exact-f32 squared distance matching numpy: square elementwise, then
// sequential sum ((dx2+dy2)+dz2). contract(off) forbids fma fusion so this
// matches numpy bit-for-bit regardless of -ffp-contract=fast default.
__device__ __forceinline__ float dist2(float ax, float ay, float az,
                                       float bx, float by, float bz) {
#pragma clang fp contract(off)
    float dx = ax - bx, dy = ay - by, dz = az - bz;
    return (dx * dx + dy * dy) + dz * dz;
}

// One DPP step of a u64 (hi,lo) max-reduce. CTRL must be an immediate ->
// template parameter. bound_ctrl=true: invalid source lanes read 0, and
// (0,0) never wins because all real keys have klo = ~idx != 0.
template <int CTRL>
__device__ __forceinline__ void dpp_max_step(unsigned int& khi, unsigned int& klo) {
    unsigned int ohi = (unsigned int)__builtin_amdgcn_update_dpp(
        0, (int)khi, CTRL, 0xf, 0xf, true);
    unsigned int olo = (unsigned int)__builtin_amdgcn_update_dpp(
        0, (int)klo, CTRL, 0xf, 0xf, true);
    bool take = (ohi > khi) || (ohi == khi && olo > klo);
    khi = take ? ohi : khi;
    klo = take ? olo : klo;
}

// Zero the progress flags (d_ws is poisoned 0xAA before every launch).
__global__ void init_kernel(int* __restrict__ prog) {
    if (threadIdx.x < 128) prog[threadIdx.x] = 0;
}

// Role-union LDS: fps needs the big coord arrays; consumers need the MLP
// tiles. Union ~100 KB -> 1 block/CU for both roles (no artificial pad).
union SharedU {
    struct {
        float sxp[kP], syp[kP], szp[kP];       // SoA cloud copy
        unsigned short widx[kM];               // winner index per iteration
        unsigned long long part[2][4];         // ping-pong wave partials
    } f;
    struct {
        float msg[kK][36];                     // 35 used, stride 36
        float h1[kK][kH];
        float h2[kK][kH];
        float red[2][kO];
        int   s_nb[kK];
        float s_cent[3];
        int   s_cnt;
    } c;
};

// ---------------------------------------------------------------------------
// Mega-kernel: producer/consumer overlap.
//  blocks 0..7       : FPS for cloud b (r6-proven math incl. LDS coords,
//                      bit-exact). Publishes each centroid to `stage`
//                      (agent-scope relaxed atomic stores) and a progress
//                      counter (release) every 32 iterations.
//  blocks 8..8+16383 : one centroid each, cloud-rotated (b = i&7) so resident
//                      blocks unlock at 8x the per-cloud fps rate. Spin on
//                      prog[b] (lane-0 poll + s_sleep), read cent via atomic
//                      loads, then ball query (wave 0, LDS-local) + gather +
//                      MLP + masked max.
// ---------------------------------------------------------------------------
__global__ __launch_bounds__(256, 1) void mega_kernel(
    const float* __restrict__ pos, const float* __restrict__ x,
    const float* __restrict__ W1, const float* __restrict__ b1,
    const float* __restrict__ W2, const float* __restrict__ b2,
    const float* __restrict__ W3, const float* __restrict__ b3,
    unsigned int* __restrict__ stage, int* __restrict__ prog,
    float* __restrict__ cent_out, float* __restrict__ feat_out,
    float* __restrict__ batch_out) {
    __shared__ SharedU sh;

    const int tid = threadIdx.x;
    const int wave = tid >> 6, lane = tid & 63;

    if (blockIdx.x < (unsigned)kB) {
        // ======================= FPS role =======================
        const int b = blockIdx.x;
        const float* pb = pos + (size_t)b * kP * 3;

        v2f px2[16], py2[16], pz2[16], dd2[16];
#pragma unroll
        for (int q = 0; q < 32; ++q) {
            int i = tid + q * 256;
            float X = pb[i * 3 + 0];
            float Y = pb[i * 3 + 1];
            float Z = pb[i * 3 + 2];
            sh.f.sxp[i] = X; sh.f.syp[i] = Y; sh.f.szp[i] = Z;
            if (q & 1) { px2[q >> 1].y = X; py2[q >> 1].y = Y; pz2[q >> 1].y = Z; }
            else       { px2[q >> 1].x = X; py2[q >> 1].x = Y; pz2[q >> 1].x = Z; }
        }
#pragma unroll
        for (int q = 0; q < 16; ++q) dd2[q] = (v2f){INFINITY, INFINITY};

        if (tid == 0) sh.f.widx[0] = 0;
        __syncthreads();

        // first selected point: original index 0
        float lx = sh.f.sxp[0], ly = sh.f.syp[0], lz = sh.f.szp[0];
        if (tid == 0) {
            size_t o = (size_t)(b * kM) * 3;
            __hip_atomic_store(&stage[o + 0], __float_as_uint(lx),
                               __ATOMIC_RELAXED, __HIP_MEMORY_SCOPE_AGENT);
            __hip_atomic_store(&stage[o + 1], __float_as_uint(ly),
                               __ATOMIC_RELAXED, __HIP_MEMORY_SCOPE_AGENT);
            __hip_atomic_store(&stage[o + 2], __float_as_uint(lz),
                               __ATOMIC_RELAXED, __HIP_MEMORY_SCOPE_AGENT);
            __hip_atomic_store(&prog[b * 16], 1,
                               __ATOMIC_RELEASE, __HIP_MEMORY_SCOPE_AGENT);
        }

        for (int m = 1; m < kM; ++m) {
            // --- packed dd update (exact: pk mul/add, contract off) ---
            v2f lxv = {lx, lx}, lyv = {ly, ly}, lzv = {lz, lz};
#pragma unroll
            for (int q = 0; q < 16; ++q) {
#pragma clang fp contract(off)
                v2f dx = px2[q] - lxv;
                v2f dy = py2[q] - lyv;
                v2f dz = pz2[q] - lzv;
                v2f d2 = (dx * dx + dy * dy) + dz * dz;
                dd2[q].x = fminf(dd2[q].x, d2.x);
                dd2[q].y = fminf(dd2[q].y, d2.y);
            }

            // --- thread max (balanced pairwise-max tree over 16 float2) ---
            v2f t0 = {fmaxf(dd2[0].x, dd2[0].y), fmaxf(dd2[1].x, dd2[1].y)};
            v2f t1 = {fmaxf(dd2[2].x, dd2[2].y), fmaxf(dd2[3].x, dd2[3].y)};
            v2f t2 = {fmaxf(dd2[4].x, dd2[4].y), fmaxf(dd2[5].x, dd2[5].y)};
            v2f t3 = {fmaxf(dd2[6].x, dd2[6].y), fmaxf(dd2[7].x, dd2[7].y)};
            v2f t4 = {fmaxf(dd2[8].x, dd2[8].y), fmaxf(dd2[9].x, dd2[9].y)};
            v2f t5 = {fmaxf(dd2[10].x, dd2[10].y), fmaxf(dd2[11].x, dd2[11].y)};
            v2f t6 = {fmaxf(dd2[12].x, dd2[12].y), fmaxf(dd2[13].x, dd2[13].y)};
            v2f t7 = {fmaxf(dd2[14].x, dd2[14].y), fmaxf(dd2[15].x, dd2[15].y)};
            float u0 = fmaxf(fmaxf(t0.x, t0.y), fmaxf(t1.x, t1.y));
            float u1 = fmaxf(fmaxf(t2.x, t2.y), fmaxf(t3.x, t3.y));
            float u2 = fmaxf(fmaxf(t4.x, t4.y), fmaxf(t5.x, t5.y));
            float u3 = fmaxf(fmaxf(t6.x, t6.y), fmaxf(t7.x, t7.y));
            float bv = fmaxf(fmaxf(u0, u1), fmaxf(u2, u3));

            // --- grouped locate: lowest owned slot with dd == bv ---
            int lqs[4];
#pragma unroll
            for (int g = 0; g < 4; ++g) {
                int t = 64;
#pragma unroll
                for (int s = 7; s >= 0; --s) {
                    int sl = g * 8 + s;
                    float v = (sl & 1) ? dd2[sl >> 1].y : dd2[sl >> 1].x;
                    t = (v == bv) ? sl : t;
                }
                lqs[g] = t;
            }
            int bq = lqs[3];
            bq = (lqs[2] < 64) ? lqs[2] : bq;
            bq = (lqs[1] < 64) ? lqs[1] : bq;
            bq = (lqs[0] < 64) ? lqs[0] : bq;

            unsigned int bidx = (unsigned int)(tid + bq * 256);
            unsigned int khi = __float_as_uint(bv);
            unsigned int klo = (unsigned int)(~bidx);

            // --- wave u64 max-reduce via DPP (lane 63 = wave max) ---
            dpp_max_step<0x111>(khi, klo);   // row_shr:1
            dpp_max_step<0x112>(khi, klo);   // row_shr:2
            dpp_max_step<0x114>(khi, klo);   // row_shr:4
            dpp_max_step<0x118>(khi, klo);   // row_shr:8
            dpp_max_step<0x142>(khi, klo);   // row_bcast:15
            dpp_max_step<0x143>(khi, klo);   // row_bcast:31
            if (lane == 63)
                sh.f.part[m & 1][wave] = ((unsigned long long)khi << 32) | klo;
            __syncthreads();

            // --- block winner from 4 partials (broadcast reads) ---
            unsigned long long k = sh.f.part[m & 1][0];
#pragma unroll
            for (int w = 1; w < 4; ++w) {
                unsigned long long o = sh.f.part[m & 1][w];
                if (o > k) k = o;
            }
            unsigned int wi = ~(unsigned int)k;          // original index
            lx = sh.f.sxp[wi]; ly = sh.f.syp[wi]; lz = sh.f.szp[wi];

            if (tid == 0) {
                sh.f.widx[m] = (unsigned short)wi;
                size_t o = (size_t)(b * kM + m) * 3;
                __hip_atomic_store(&stage[o + 0], __float_as_uint(lx),
                                   __ATOMIC_RELAXED, __HIP_MEMORY_SCOPE_AGENT);
                __hip_atomic_store(&stage[o + 1], __float_as_uint(ly),
                                   __ATOMIC_RELAXED, __HIP_MEMORY_SCOPE_AGENT);
                __hip_atomic_store(&stage[o + 2], __float_as_uint(lz),
                                   __ATOMIC_RELAXED, __HIP_MEMORY_SCOPE_AGENT);
                if ((m & 31) == 31)
                    __hip_atomic_store(&prog[b * 16], m + 1,
                                       __ATOMIC_RELEASE, __HIP_MEMORY_SCOPE_AGENT);
            }
            // ping-pong part[] + next barrier order the WAR hazard
        }
        __syncthreads();

        // cooperative centroid writeout (bit-exact copies of input coords)
#pragma unroll
        for (int q = 0; q < kM / 256; ++q) {
            int i = tid + q * 256;
            unsigned int wi = sh.f.widx[i];
            size_t o = (size_t)(b * kM + i) * 3;
            cent_out[o + 0] = sh.f.sxp[wi];
            cent_out[o + 1] = sh.f.syp[wi];
            cent_out[o + 2] = sh.f.szp[wi];
        }
        return;
    }

    // ======================= consumer role =======================
    const int i = (int)blockIdx.x - kB;
    const int b = i & 7;          // cloud-rotated dispatch
    const int cl = i >> 3;        // centroid index within cloud
    const int c = b * kM + cl;    // global centroid id

    // wait until fps has published this centroid
    if (tid == 0) {
        while (__hip_atomic_load(&prog[b * 16], __ATOMIC_ACQUIRE,
                                 __HIP_MEMORY_SCOPE_AGENT) < cl + 1)
            __builtin_amdgcn_s_sleep(16);
    }
    __syncthreads();

    if (tid < 3) {
        unsigned int u = __hip_atomic_load(&stage[(size_t)c * 3 + tid],
                                           __ATOMIC_RELAXED, __HIP_MEMORY_SCOPE_AGENT);
        sh.c.s_cent[tid] = __uint_as_float(u);
    }
    __syncthreads();

    // --- ball query (wave 0): ballot + prefix popcount, lowest indices
    // first (== reference sort+take-K), early exit at K ---
    if (wave == 0) {
        const float R2 = (float)(0.2 * 0.2);
        float cx = sh.c.s_cent[0], cy = sh.c.s_cent[1], cz = sh.c.s_cent[2];
        const float* pb = pos + (size_t)b * kP * 3;
        int cnt = 0;
        for (int p0 = 0; p0 < kP && cnt < kK; p0 += 64) {
            int idx = p0 + lane;
            float X = pb[idx * 3 + 0], Y = pb[idx * 3 + 1], Z = pb[idx * 3 + 2];
            float d2 = dist2(X, Y, Z, cx, cy, cz);
            bool in = d2 <= R2;
            unsigned long long mask = __ballot(in);
            int rank = __popcll(mask & ((1ull << lane) - 1ull));
            if (in && cnt + rank < kK) sh.c.s_nb[cnt + rank] = idx;
            cnt = min(cnt + (int)__popcll(mask), kK);
        }
        if (lane == 0) { sh.c.s_cnt = cnt; batch_out[c] = (float)b; }
    }
    __syncthreads();
    const int cnt = sh.c.s_cnt;

    // --- gather msg = [x_j (32) | pos_j - cent (3)] ---
    for (int u = tid; u < kK * 35; u += 256) {
        int k = u / 35, f = u - k * 35;
        float v = 0.0f;
        if (k < cnt) {
            int n = sh.c.s_nb[k];
            if (f < 32) v = x[((size_t)b * kP + n) * kF + f];
            else        v = pos[((size_t)b * kP + n) * 3 + (f - 32)] - sh.c.s_cent[f - 32];
        }
        sh.c.msg[k][f] = v;
    }
    __syncthreads();

    // layer 1: 35 -> 64
    {
        int j = tid & 63, k0 = tid >> 6;
        float w[35];
#pragma unroll
        for (int q = 0; q < 35; ++q) w[q] = W1[q * 64 + j];
        float bb = b1[j];
#pragma unroll
        for (int kk = 0; kk < 16; ++kk) {
            int k = k0 * 16 + kk;
            float acc = bb;
#pragma unroll
            for (int q = 0; q < 35; ++q) acc += sh.c.msg[k][q] * w[q];
            sh.c.h1[k][j] = fmaxf(acc, 0.0f);
        }
    }
    __syncthreads();

    // layer 2: 64 -> 64
    {
        int j = tid & 63, k0 = tid >> 6;
        float w[64];
#pragma unroll
        for (int q = 0; q < 64; ++q) w[q] = W2[q * 64 + j];
        float bb = b2[j];
#pragma unroll
        for (int kk = 0; kk < 16; ++kk) {
            int k = k0 * 16 + kk;
            float acc = bb;
#pragma unroll
            for (int q = 0; q < 64; ++q) acc += sh.c.h1[k][q] * w[q];
            sh.c.h2[k][j] = fmaxf(acc, 0.0f);
        }
    }
    __syncthreads();

    // layer 3: 64 -> 128, fused masked max over valid k
    {
        int j = tid & 127, k0 = tid >> 7;
        float w[64];
#pragma unroll
        for (int q = 0; q < 64; ++q) w[q] = W3[q * 128 + j];
        float bb = b3[j];
        float best = -INFINITY;
        for (int kk = 0; kk < 32; ++kk) {
            int k = k0 * 32 + kk;      // wave-uniform bound
            if (k >= cnt) break;
            float acc = bb;
#pragma unroll
            for (int q = 0; q < 64; ++q) acc += sh.c.h2[k][q] * w[q];
            best = fmaxf(best, fmaxf(acc, 0.0f));
        }
        sh.c.red[k0][j] = best;
    }
    __syncthreads();

    if (tid < kO) {
        float o = fmaxf(sh.c.red[0][tid], sh.c.red[1][tid]);   // cnt>=1 -> valid
        feat_out[(size_t)c * kO + tid] = o;
    }
}

// ---------------------------------------------------------------------------
extern "C" void kernel_launch(void* const* d_in, const int* in_sizes, int n_in,
                              void* d_out, int out_size, void* d_ws, size_t ws_size,
                              hipStream_t stream) {
    const float* pos = (const float*)d_in[0];
    // d_in[1] = batch (unused; implied by layout)
    const float* x  = (const float*)d_in[2];
    const float* W1 = (const float*)d_in[3];
    const float* b1 = (const float*)d_in[4];
    const float* W2 = (const float*)d_in[5];
    const float* b2 = (const float*)d_in[6];
    const float* W3 = (const float*)d_in[7];
    const float* b3 = (const float*)d_in[8];

    float* out = (float*)d_out;
    float* cent_out  = out;                                   // [B*M, 3]
    float* feat_out  = out + (size_t)kB * kM * 3;             // [B*M, 128]
    float* batch_out = out + (size_t)kB * kM * (3 + kO);      // [B*M]

    char* ws = (char*)d_ws;
    int* prog           = (int*)ws;                           // 128 ints (strided)
    unsigned int* stage = (unsigned int*)(ws + 512);          // B*M*3 uints

    init_kernel<<<1, 128, 0, stream>>>(prog);
    mega_kernel<<<kB + kB * kM, 256, 0, stream>>>(
        pos, x, W1, b1, W2, b2, W3, b3, stage, prog,
        cent_out, feat_out, batch_out);
}

// Round 11
// 2492.075 us; speedup vs baseline: 1.2924x; 1.0134x over previous
//
#include <hip/hip_runtime.h>
#include <stdint.h>
#include <math.h>

// Problem constants (from reference)
constexpr int kB = 8;      // clouds
constexpr int kP = 8192;   // points per cloud
constexpr int kF = 32;     // feature dim
constexpr int kM = 2048;   // centroids per cloud (P * 0.25)
constexpr int kK = 64;     // max neighbors
constexpr int kH = 64;     // hidden dim
constexpr int kO = 128;    // output dim

typedef float v2f __attribute__((ext_vector_type(2)));

// Exact-f32 squared distance matching numpy: square elementwise, then
// sequential sum ((dx2+dy2)+dz2). contract(off) forbids fma fusion so this
// matches numpy bit-for-bit regardless of -ffp-contract=fast default.
__device__ __forceinline__ float dist2(float ax, float ay, float az,
                                       float bx, float by, float bz) {
#pragma clang fp contract(off)
    float dx = ax - bx, dy = ay - by, dz = az - bz;
    return (dx * dx + dy * dy) + dz * dz;
}

// One DPP step of a u64 (hi,lo) max-reduce. CTRL must be an immediate ->
// template parameter. bound_ctrl=true: invalid source lanes read 0, and
// (0,0) never wins because all real keys have klo = ~idx != 0.
template <int CTRL>
__device__ __forceinline__ void dpp_max_step(unsigned int& khi, unsigned int& klo) {
    unsigned int ohi = (unsigned int)__builtin_amdgcn_update_dpp(
        0, (int)khi, CTRL, 0xf, 0xf, true);
    unsigned int olo = (unsigned int)__builtin_amdgcn_update_dpp(
        0, (int)klo, CTRL, 0xf, 0xf, true);
    bool take = (ohi > khi) || (ohi == khi && olo > klo);
    khi = take ? ohi : khi;
    klo = take ? olo : klo;
}

// Zero the progress flags (d_ws is poisoned 0xAA before every launch).
__global__ void init_kernel(int* __restrict__ prog) {
    if (threadIdx.x < 128) prog[threadIdx.x] = 0;
}

// Role-union LDS: fps needs the big coord arrays; consumers need the MLP
// tiles. Union ~100 KB -> 1 block/CU for both roles.
union SharedU {
    struct {
        float sxp[kP], syp[kP], szp[kP];       // SoA cloud copy
        unsigned short widx[kM];               // winner index per iteration
        unsigned long long part[2][4];         // ping-pong wave partials
    } f;
    struct {
        float msg[kK][36];                     // 35 used, stride 36
        float h1[kK][kH];
        float h2[kK][kH];
        float red[2][kO];
        int   s_nb[kK];
        float s_cent[3];
        int   s_cnt;
    } c;
};

// ---------------------------------------------------------------------------
// Mega-kernel: producer/consumer overlap.
//  blocks 0..7       : FPS for cloud b (r6/r8-proven math, bit-exact).
//                      ZERO global stores inside the per-iteration loop;
//                      every 32 iterations threads 0..95 cooperatively
//                      publish the batch to `stage` (relaxed agent stores),
//                      one extra __syncthreads drains them, then tid0
//                      releases prog[b].
//  blocks 8..8+16383 : one centroid each, cloud-rotated (b = i&7). Spin on
//                      prog[b] with deficit-based s_sleep backoff, read cent
//                      via atomic loads, then ball query (wave 0, LDS-local)
//                      + gather + MLP + masked max.
// ---------------------------------------------------------------------------
__global__ __launch_bounds__(256, 1) void mega_kernel(
    const float* __restrict__ pos, const float* __restrict__ x,
    const float* __restrict__ W1, const float* __restrict__ b1,
    const float* __restrict__ W2, const float* __restrict__ b2,
    const float* __restrict__ W3, const float* __restrict__ b3,
    unsigned int* __restrict__ stage, int* __restrict__ prog,
    float* __restrict__ cent_out, float* __restrict__ feat_out,
    float* __restrict__ batch_out) {
    __shared__ SharedU sh;

    const int tid = threadIdx.x;
    const int wave = tid >> 6, lane = tid & 63;

    if (blockIdx.x < (unsigned)kB) {
        // ======================= FPS role =======================
        const int b = blockIdx.x;
        const float* pb = pos + (size_t)b * kP * 3;

        v2f px2[16], py2[16], pz2[16], dd2[16];
#pragma unroll
        for (int q = 0; q < 32; ++q) {
            int i = tid + q * 256;
            float X = pb[i * 3 + 0];
            float Y = pb[i * 3 + 1];
            float Z = pb[i * 3 + 2];
            sh.f.sxp[i] = X; sh.f.syp[i] = Y; sh.f.szp[i] = Z;
            if (q & 1) { px2[q >> 1].y = X; py2[q >> 1].y = Y; pz2[q >> 1].y = Z; }
            else       { px2[q >> 1].x = X; py2[q >> 1].x = Y; pz2[q >> 1].x = Z; }
        }
#pragma unroll
        for (int q = 0; q < 16; ++q) dd2[q] = (v2f){INFINITY, INFINITY};

        if (tid == 0) sh.f.widx[0] = 0;
        __syncthreads();

        // first selected point: original index 0 — publish immediately so
        // cl==0 consumers can start.
        float lx = sh.f.sxp[0], ly = sh.f.syp[0], lz = sh.f.szp[0];
        if (tid == 0) {
            size_t o = (size_t)(b * kM) * 3;
            __hip_atomic_store(&stage[o + 0], __float_as_uint(lx),
                               __ATOMIC_RELAXED, __HIP_MEMORY_SCOPE_AGENT);
            __hip_atomic_store(&stage[o + 1], __float_as_uint(ly),
                               __ATOMIC_RELAXED, __HIP_MEMORY_SCOPE_AGENT);
            __hip_atomic_store(&stage[o + 2], __float_as_uint(lz),
                               __ATOMIC_RELAXED, __HIP_MEMORY_SCOPE_AGENT);
            __hip_atomic_store(&prog[b * 16], 1,
                               __ATOMIC_RELEASE, __HIP_MEMORY_SCOPE_AGENT);
        }

        for (int m = 1; m < kM; ++m) {
            // --- packed dd update (exact: pk mul/add, contract off) ---
            v2f lxv = {lx, lx}, lyv = {ly, ly}, lzv = {lz, lz};
#pragma unroll
            for (int q = 0; q < 16; ++q) {
#pragma clang fp contract(off)
                v2f dx = px2[q] - lxv;
                v2f dy = py2[q] - lyv;
                v2f dz = pz2[q] - lzv;
                v2f d2 = (dx * dx + dy * dy) + dz * dz;
                dd2[q].x = fminf(dd2[q].x, d2.x);
                dd2[q].y = fminf(dd2[q].y, d2.y);
            }

            // --- thread max (balanced pairwise-max tree over 16 float2) ---
            v2f t0 = {fmaxf(dd2[0].x, dd2[0].y), fmaxf(dd2[1].x, dd2[1].y)};
            v2f t1 = {fmaxf(dd2[2].x, dd2[2].y), fmaxf(dd2[3].x, dd2[3].y)};
            v2f t2 = {fmaxf(dd2[4].x, dd2[4].y), fmaxf(dd2[5].x, dd2[5].y)};
            v2f t3 = {fmaxf(dd2[6].x, dd2[6].y), fmaxf(dd2[7].x, dd2[7].y)};
            v2f t4 = {fmaxf(dd2[8].x, dd2[8].y), fmaxf(dd2[9].x, dd2[9].y)};
            v2f t5 = {fmaxf(dd2[10].x, dd2[10].y), fmaxf(dd2[11].x, dd2[11].y)};
            v2f t6 = {fmaxf(dd2[12].x, dd2[12].y), fmaxf(dd2[13].x, dd2[13].y)};
            v2f t7 = {fmaxf(dd2[14].x, dd2[14].y), fmaxf(dd2[15].x, dd2[15].y)};
            float u0 = fmaxf(fmaxf(t0.x, t0.y), fmaxf(t1.x, t1.y));
            float u1 = fmaxf(fmaxf(t2.x, t2.y), fmaxf(t3.x, t3.y));
            float u2 = fmaxf(fmaxf(t4.x, t4.y), fmaxf(t5.x, t5.y));
            float u3 = fmaxf(fmaxf(t6.x, t6.y), fmaxf(t7.x, t7.y));
            float bv = fmaxf(fmaxf(u0, u1), fmaxf(u2, u3));

            // --- grouped locate: lowest owned slot with dd == bv ---
            int lqs[4];
#pragma unroll
            for (int g = 0; g < 4; ++g) {
                int t = 64;
#pragma unroll
                for (int s = 7; s >= 0; --s) {
                    int sl = g * 8 + s;
                    float v = (sl & 1) ? dd2[sl >> 1].y : dd2[sl >> 1].x;
                    t = (v == bv) ? sl : t;
                }
                lqs[g] = t;
            }
            int bq = lqs[3];
            bq = (lqs[2] < 64) ? lqs[2] : bq;
            bq = (lqs[1] < 64) ? lqs[1] : bq;
            bq = (lqs[0] < 64) ? lqs[0] : bq;

            unsigned int bidx = (unsigned int)(tid + bq * 256);
            unsigned int khi = __float_as_uint(bv);
            unsigned int klo = (unsigned int)(~bidx);

            // --- wave u64 max-reduce via DPP (lane 63 = wave max) ---
            dpp_max_step<0x111>(khi, klo);   // row_shr:1
            dpp_max_step<0x112>(khi, klo);   // row_shr:2
            dpp_max_step<0x114>(khi, klo);   // row_shr:4
            dpp_max_step<0x118>(khi, klo);   // row_shr:8
            dpp_max_step<0x142>(khi, klo);   // row_bcast:15
            dpp_max_step<0x143>(khi, klo);   // row_bcast:31
            if (lane == 63)
                sh.f.part[m & 1][wave] = ((unsigned long long)khi << 32) | klo;
            __syncthreads();

            // --- block winner from 4 partials (broadcast reads) ---
            unsigned long long k = sh.f.part[m & 1][0];
#pragma unroll
            for (int w = 1; w < 4; ++w) {
                unsigned long long o = sh.f.part[m & 1][w];
                if (o > k) k = o;
            }
            unsigned int wi = ~(unsigned int)k;          // original index
            lx = sh.f.sxp[wi]; ly = sh.f.syp[wi]; lz = sh.f.szp[wi];
            if (tid == 0) sh.f.widx[m] = (unsigned short)wi;

            // --- batched publish every 32 iterations (off critical path) ---
            if ((m & 31) == 31) {
                int m0 = m - 31;
                if (tid < 96) {
                    int mm = m0 + tid / 3;   // centroid in batch
                    int comp = tid % 3;
                    // widx[m0..m-1] visible (written before this iter's
                    // barrier); current winner known in-register by all.
                    unsigned int w2 = (mm == m) ? wi
                                                : (unsigned int)sh.f.widx[mm];
                    float v = (comp == 0) ? sh.f.sxp[w2]
                            : (comp == 1) ? sh.f.syp[w2] : sh.f.szp[w2];
                    __hip_atomic_store(&stage[(size_t)(b * kM + mm) * 3 + comp],
                                       __float_as_uint(v),
                                       __ATOMIC_RELAXED, __HIP_MEMORY_SCOPE_AGENT);
                }
                __syncthreads();   // drains publishing waves' stores (vmcnt)
                if (tid == 0)
                    __hip_atomic_store(&prog[b * 16], m + 1,
                                       __ATOMIC_RELEASE, __HIP_MEMORY_SCOPE_AGENT);
            }
            // ping-pong part[] + next barrier order the WAR hazard
        }
        __syncthreads();

        // cooperative centroid writeout (bit-exact copies of input coords)
#pragma unroll
        for (int q = 0; q < kM / 256; ++q) {
            int i = tid + q * 256;
            unsigned int wi = sh.f.widx[i];
            size_t o = (size_t)(b * kM + i) * 3;
            cent_out[o + 0] = sh.f.sxp[wi];
            cent_out[o + 1] = sh.f.syp[wi];
            cent_out[o + 2] = sh.f.szp[wi];
        }
        return;
    }

    // ======================= consumer role =======================
    const int i = (int)blockIdx.x - kB;
    const int b = i & 7;          // cloud-rotated dispatch
    const int cl = i >> 3;        // centroid index within cloud
    const int c = b * kM + cl;    // global centroid id

    // wait until fps has published this centroid (deficit-based backoff)
    if (tid == 0) {
        int p;
        while ((p = __hip_atomic_load(&prog[b * 16], __ATOMIC_ACQUIRE,
                                      __HIP_MEMORY_SCOPE_AGENT)) < cl + 1) {
            if (cl + 1 - p > 128) __builtin_amdgcn_s_sleep(64);
            else                  __builtin_amdgcn_s_sleep(8);
        }
    }
    __syncthreads();

    if (tid < 3) {
        unsigned int u = __hip_atomic_load(&stage[(size_t)c * 3 + tid],
                                           __ATOMIC_RELAXED, __HIP_MEMORY_SCOPE_AGENT);
        sh.c.s_cent[tid] = __uint_as_float(u);
    }
    __syncthreads();

    // --- ball query (wave 0): ballot + prefix popcount, lowest indices
    // first (== reference sort+take-K), early exit at K ---
    if (wave == 0) {
        const float R2 = (float)(0.2 * 0.2);
        float cx = sh.c.s_cent[0], cy = sh.c.s_cent[1], cz = sh.c.s_cent[2];
        const float* pb = pos + (size_t)b * kP * 3;
        int cnt = 0;
        for (int p0 = 0; p0 < kP && cnt < kK; p0 += 64) {
            int idx = p0 + lane;
            float X = pb[idx * 3 + 0], Y = pb[idx * 3 + 1], Z = pb[idx * 3 + 2];
            float d2 = dist2(X, Y, Z, cx, cy, cz);
            bool in = d2 <= R2;
            unsigned long long mask = __ballot(in);
            int rank = __popcll(mask & ((1ull << lane) - 1ull));
            if (in && cnt + rank < kK) sh.c.s_nb[cnt + rank] = idx;
            cnt = min(cnt + (int)__popcll(mask), kK);
        }
        if (lane == 0) { sh.c.s_cnt = cnt; batch_out[c] = (float)b; }
    }
    __syncthreads();
    const int cnt = sh.c.s_cnt;

    // --- gather msg = [x_j (32) | pos_j - cent (3)] ---
    for (int u = tid; u < kK * 35; u += 256) {
        int k = u / 35, f = u - k * 35;
        float v = 0.0f;
        if (k < cnt) {
            int n = sh.c.s_nb[k];
            if (f < 32) v = x[((size_t)b * kP + n) * kF + f];
            else        v = pos[((size_t)b * kP + n) * 3 + (f - 32)] - sh.c.s_cent[f - 32];
        }
        sh.c.msg[k][f] = v;
    }
    __syncthreads();

    // layer 1: 35 -> 64
    {
        int j = tid & 63, k0 = tid >> 6;
        float w[35];
#pragma unroll
        for (int q = 0; q < 35; ++q) w[q] = W1[q * 64 + j];
        float bb = b1[j];
#pragma unroll
        for (int kk = 0; kk < 16; ++kk) {
            int k = k0 * 16 + kk;
            float acc = bb;
#pragma unroll
            for (int q = 0; q < 35; ++q) acc += sh.c.msg[k][q] * w[q];
            sh.c.h1[k][j] = fmaxf(acc, 0.0f);
        }
    }
    __syncthreads();

    // layer 2: 64 -> 64
    {
        int j = tid & 63, k0 = tid >> 6;
        float w[64];
#pragma unroll
        for (int q = 0; q < 64; ++q) w[q] = W2[q * 64 + j];
        float bb = b2[j];
#pragma unroll
        for (int kk = 0; kk < 16; ++kk) {
            int k = k0 * 16 + kk;
            float acc = bb;
#pragma unroll
            for (int q = 0; q < 64; ++q) acc += sh.c.h1[k][q] * w[q];
            sh.c.h2[k][j] = fmaxf(acc, 0.0f);
        }
    }
    __syncthreads();

    // layer 3: 64 -> 128, fused masked max over valid k
    {
        int j = tid & 127, k0 = tid >> 7;
        float w[64];
#pragma unroll
        for (int q = 0; q < 64; ++q) w[q] = W3[q * 128 + j];
        float bb = b3[j];
        float best = -INFINITY;
        for (int kk = 0; kk < 32; ++kk) {
            int k = k0 * 32 + kk;      // wave-uniform bound
            if (k >= cnt) break;
            float acc = bb;
#pragma unroll
            for (int q = 0; q < 64; ++q) acc += sh.c.h2[k][q] * w[q];
            best = fmaxf(best, fmaxf(acc, 0.0f));
        }
        sh.c.red[k0][j] = best;
    }
    __syncthreads();

    if (tid < kO) {
        float o = fmaxf(sh.c.red[0][tid], sh.c.red[1][tid]);   // cnt>=1 -> valid
        feat_out[(size_t)c * kO + tid] = o;
    }
}

// ---------------------------------------------------------------------------
extern "C" void kernel_launch(void* const* d_in, const int* in_sizes, int n_in,
                              void* d_out, int out_size, void* d_ws, size_t ws_size,
                              hipStream_t stream) {
    const float* pos = (const float*)d_in[0];
    // d_in[1] = batch (unused; implied by layout)
    const float* x  = (const float*)d_in[2];
    const float* W1 = (const float*)d_in[3];
    const float* b1 = (const float*)d_in[4];
    const float* W2 = (const float*)d_in[5];
    const float* b2 = (const float*)d_in[6];
    const float* W3 = (const float*)d_in[7];
    const float* b3 = (const float*)d_in[8];

    float* out = (float*)d_out;
    float* cent_out  = out;                                   // [B*M, 3]
    float* feat_out  = out + (size_t)kB * kM * 3;             // [B*M, 128]
    float* batch_out = out + (size_t)kB * kM * (3 + kO);      // [B*M]

    char* ws = (char*)d_ws;
    int* prog           = (int*)ws;                           // 128 ints (strided)
    unsigned int* stage = (unsigned int*)(ws + 512);          // B*M*3 uints

    init_kernel<<<1, 128, 0, stream>>>(prog);
    mega_kernel<<<kB + kB * kM, 256, 0, stream>>>(
        pos, x, W1, b1, W2, b2, W3, b3, stage, prog,
        cent_out, feat_out, batch_out);
}

// Round 12
// 2183.160 us; speedup vs baseline: 1.4752x; 1.1415x over previous
//
#include <hip/hip_runtime.h>
#include <stdint.h>
#include <math.h>

// Problem constants (from reference)
constexpr int kB = 8;      // clouds
constexpr int kP = 8192;   // points per cloud
constexpr int kF = 32;     // feature dim
constexpr int kM = 2048;   // centroids per cloud (P * 0.25)
constexpr int kK = 64;     // max neighbors
constexpr int kH = 64;     // hidden dim
constexpr int kO = 128;    // output dim

typedef float v2f __attribute__((ext_vector_type(2)));
typedef _Float16 h2f __attribute__((ext_vector_type(2)));

// Exact-f32 squared distance matching numpy: square elementwise, then
// sequential sum ((dx2+dy2)+dz2). contract(off) forbids fma fusion so this
// matches numpy bit-for-bit regardless of -ffp-contract=fast default.
__device__ __forceinline__ float dist2(float ax, float ay, float az,
                                       float bx, float by, float bz) {
#pragma clang fp contract(off)
    float dx = ax - bx, dy = ay - by, dz = az - bz;
    return (dx * dx + dy * dy) + dz * dz;
}

// One DPP step of a u64 (hi,lo) max-reduce. CTRL must be an immediate ->
// template parameter. bound_ctrl=true: invalid source lanes read 0, and
// (0,0) never wins because all real keys have klo = ~idx != 0.
template <int CTRL>
__device__ __forceinline__ void dpp_max_step(unsigned int& khi, unsigned int& klo) {
    unsigned int ohi = (unsigned int)__builtin_amdgcn_update_dpp(
        0, (int)khi, CTRL, 0xf, 0xf, true);
    unsigned int olo = (unsigned int)__builtin_amdgcn_update_dpp(
        0, (int)klo, CTRL, 0xf, 0xf, true);
    bool take = (ohi > khi) || (ohi == khi && olo > klo);
    khi = take ? ohi : khi;
    klo = take ? olo : klo;
}

// Zero the progress flags (d_ws is poisoned 0xAA before every launch).
__global__ void init_kernel(int* __restrict__ prog) {
    if (threadIdx.x < 128) prog[threadIdx.x] = 0;
}

// Role-union LDS: fps needs the big coord arrays; consumers need the MLP
// tiles (now fp16 activations). Union ~100 KB -> 1 block/CU for both roles.
union SharedU {
    struct {
        float sxp[kP], syp[kP], szp[kP];       // SoA cloud copy
        unsigned short widx[kM];               // winner index per iteration
        unsigned long long part[2][4];         // ping-pong wave partials
    } f;
    struct {
        _Float16 msg[kK][36];                  // 35 used + zero pad
        _Float16 h1[kK][kH];
        _Float16 h2[kK][kH];
        float red[2][kO];
        int   s_nb[kK];
        float s_cent[3];
        int   s_cnt;
    } c;
};

// ---------------------------------------------------------------------------
// Mega-kernel: producer/consumer overlap.
//  blocks 0..7       : FPS for cloud b (r6/r8-proven math, bit-exact).
//                      Zero global stores in the per-iteration loop; batch
//                      publish every 32 iters (threads 0..95 -> stage,
//                      extra barrier, tid0 releases prog[b]).
//  blocks 8..8+16383 : one centroid each, cloud-rotated (b = i&7). Spin on
//                      prog[b] with deficit backoff, then ball query (wave 0,
//                      LDS-local, fp32-exact) + gather + fp16-dot2 MLP
//                      (fp32 accumulate) + masked max.
// ---------------------------------------------------------------------------
__global__ __launch_bounds__(256, 1) void mega_kernel(
    const float* __restrict__ pos, const float* __restrict__ x,
    const float* __restrict__ W1, const float* __restrict__ b1,
    const float* __restrict__ W2, const float* __restrict__ b2,
    const float* __restrict__ W3, const float* __restrict__ b3,
    unsigned int* __restrict__ stage, int* __restrict__ prog,
    float* __restrict__ cent_out, float* __restrict__ feat_out,
    float* __restrict__ batch_out) {
    __shared__ SharedU sh;

    const int tid = threadIdx.x;
    const int wave = tid >> 6, lane = tid & 63;

    if (blockIdx.x < (unsigned)kB) {
        // ======================= FPS role =======================
        const int b = blockIdx.x;
        const float* pb = pos + (size_t)b * kP * 3;

        v2f px2[16], py2[16], pz2[16], dd2[16];
#pragma unroll
        for (int q = 0; q < 32; ++q) {
            int i = tid + q * 256;
            float X = pb[i * 3 + 0];
            float Y = pb[i * 3 + 1];
            float Z = pb[i * 3 + 2];
            sh.f.sxp[i] = X; sh.f.syp[i] = Y; sh.f.szp[i] = Z;
            if (q & 1) { px2[q >> 1].y = X; py2[q >> 1].y = Y; pz2[q >> 1].y = Z; }
            else       { px2[q >> 1].x = X; py2[q >> 1].x = Y; pz2[q >> 1].x = Z; }
        }
#pragma unroll
        for (int q = 0; q < 16; ++q) dd2[q] = (v2f){INFINITY, INFINITY};

        if (tid == 0) sh.f.widx[0] = 0;
        __syncthreads();

        // first selected point: original index 0 — publish immediately so
        // cl==0 consumers can start.
        float lx = sh.f.sxp[0], ly = sh.f.syp[0], lz = sh.f.szp[0];
        if (tid == 0) {
            size_t o = (size_t)(b * kM) * 3;
            __hip_atomic_store(&stage[o + 0], __float_as_uint(lx),
                               __ATOMIC_RELAXED, __HIP_MEMORY_SCOPE_AGENT);
            __hip_atomic_store(&stage[o + 1], __float_as_uint(ly),
                               __ATOMIC_RELAXED, __HIP_MEMORY_SCOPE_AGENT);
            __hip_atomic_store(&stage[o + 2], __float_as_uint(lz),
                               __ATOMIC_RELAXED, __HIP_MEMORY_SCOPE_AGENT);
            __hip_atomic_store(&prog[b * 16], 1,
                               __ATOMIC_RELEASE, __HIP_MEMORY_SCOPE_AGENT);
        }

        for (int m = 1; m < kM; ++m) {
            // --- packed dd update (exact: pk mul/add, contract off) ---
            v2f lxv = {lx, lx}, lyv = {ly, ly}, lzv = {lz, lz};
#pragma unroll
            for (int q = 0; q < 16; ++q) {
#pragma clang fp contract(off)
                v2f dx = px2[q] - lxv;
                v2f dy = py2[q] - lyv;
                v2f dz = pz2[q] - lzv;
                v2f d2 = (dx * dx + dy * dy) + dz * dz;
                dd2[q].x = fminf(dd2[q].x, d2.x);
                dd2[q].y = fminf(dd2[q].y, d2.y);
            }

            // --- thread max (balanced pairwise-max tree over 16 float2) ---
            v2f t0 = {fmaxf(dd2[0].x, dd2[0].y), fmaxf(dd2[1].x, dd2[1].y)};
            v2f t1 = {fmaxf(dd2[2].x, dd2[2].y), fmaxf(dd2[3].x, dd2[3].y)};
            v2f t2 = {fmaxf(dd2[4].x, dd2[4].y), fmaxf(dd2[5].x, dd2[5].y)};
            v2f t3 = {fmaxf(dd2[6].x, dd2[6].y), fmaxf(dd2[7].x, dd2[7].y)};
            v2f t4 = {fmaxf(dd2[8].x, dd2[8].y), fmaxf(dd2[9].x, dd2[9].y)};
            v2f t5 = {fmaxf(dd2[10].x, dd2[10].y), fmaxf(dd2[11].x, dd2[11].y)};
            v2f t6 = {fmaxf(dd2[12].x, dd2[12].y), fmaxf(dd2[13].x, dd2[13].y)};
            v2f t7 = {fmaxf(dd2[14].x, dd2[14].y), fmaxf(dd2[15].x, dd2[15].y)};
            float u0 = fmaxf(fmaxf(t0.x, t0.y), fmaxf(t1.x, t1.y));
            float u1 = fmaxf(fmaxf(t2.x, t2.y), fmaxf(t3.x, t3.y));
            float u2 = fmaxf(fmaxf(t4.x, t4.y), fmaxf(t5.x, t5.y));
            float u3 = fmaxf(fmaxf(t6.x, t6.y), fmaxf(t7.x, t7.y));
            float bv = fmaxf(fmaxf(u0, u1), fmaxf(u2, u3));

            // --- grouped locate: lowest owned slot with dd == bv ---
            int lqs[4];
#pragma unroll
            for (int g = 0; g < 4; ++g) {
                int t = 64;
#pragma unroll
                for (int s = 7; s >= 0; --s) {
                    int sl = g * 8 + s;
                    float v = (sl & 1) ? dd2[sl >> 1].y : dd2[sl >> 1].x;
                    t = (v == bv) ? sl : t;
                }
                lqs[g] = t;
            }
            int bq = lqs[3];
            bq = (lqs[2] < 64) ? lqs[2] : bq;
            bq = (lqs[1] < 64) ? lqs[1] : bq;
            bq = (lqs[0] < 64) ? lqs[0] : bq;

            unsigned int bidx = (unsigned int)(tid + bq * 256);
            unsigned int khi = __float_as_uint(bv);
            unsigned int klo = (unsigned int)(~bidx);

            // --- wave u64 max-reduce via DPP (lane 63 = wave max) ---
            dpp_max_step<0x111>(khi, klo);   // row_shr:1
            dpp_max_step<0x112>(khi, klo);   // row_shr:2
            dpp_max_step<0x114>(khi, klo);   // row_shr:4
            dpp_max_step<0x118>(khi, klo);   // row_shr:8
            dpp_max_step<0x142>(khi, klo);   // row_bcast:15
            dpp_max_step<0x143>(khi, klo);   // row_bcast:31
            if (lane == 63)
                sh.f.part[m & 1][wave] = ((unsigned long long)khi << 32) | klo;
            __syncthreads();

            // --- block winner from 4 partials (broadcast reads) ---
            unsigned long long k = sh.f.part[m & 1][0];
#pragma unroll
            for (int w = 1; w < 4; ++w) {
                unsigned long long o = sh.f.part[m & 1][w];
                if (o > k) k = o;
            }
            unsigned int wi = ~(unsigned int)k;          // original index
            lx = sh.f.sxp[wi]; ly = sh.f.syp[wi]; lz = sh.f.szp[wi];
            if (tid == 0) sh.f.widx[m] = (unsigned short)wi;

            // --- batched publish every 32 iterations (off critical path) ---
            if ((m & 31) == 31) {
                int m0 = m - 31;
                if (tid < 96) {
                    int mm = m0 + tid / 3;   // centroid in batch
                    int comp = tid % 3;
                    unsigned int w2 = (mm == m) ? wi
                                                : (unsigned int)sh.f.widx[mm];
                    float v = (comp == 0) ? sh.f.sxp[w2]
                            : (comp == 1) ? sh.f.syp[w2] : sh.f.szp[w2];
                    __hip_atomic_store(&stage[(size_t)(b * kM + mm) * 3 + comp],
                                       __float_as_uint(v),
                                       __ATOMIC_RELAXED, __HIP_MEMORY_SCOPE_AGENT);
                }
                __syncthreads();   // drains publishing waves' stores (vmcnt)
                if (tid == 0)
                    __hip_atomic_store(&prog[b * 16], m + 1,
                                       __ATOMIC_RELEASE, __HIP_MEMORY_SCOPE_AGENT);
            }
            // ping-pong part[] + next barrier order the WAR hazard
        }
        __syncthreads();

        // cooperative centroid writeout (bit-exact copies of input coords)
#pragma unroll
        for (int q = 0; q < kM / 256; ++q) {
            int i = tid + q * 256;
            unsigned int wi = sh.f.widx[i];
            size_t o = (size_t)(b * kM + i) * 3;
            cent_out[o + 0] = sh.f.sxp[wi];
            cent_out[o + 1] = sh.f.syp[wi];
            cent_out[o + 2] = sh.f.szp[wi];
        }
        return;
    }

    // ======================= consumer role =======================
    const int i = (int)blockIdx.x - kB;
    const int b = i & 7;          // cloud-rotated dispatch
    const int cl = i >> 3;        // centroid index within cloud
    const int c = b * kM + cl;    // global centroid id

    // wait until fps has published this centroid (deficit-based backoff)
    if (tid == 0) {
        int p;
        while ((p = __hip_atomic_load(&prog[b * 16], __ATOMIC_ACQUIRE,
                                      __HIP_MEMORY_SCOPE_AGENT)) < cl + 1) {
            if (cl + 1 - p > 128) __builtin_amdgcn_s_sleep(64);
            else                  __builtin_amdgcn_s_sleep(8);
        }
    }
    __syncthreads();

    if (tid < 3) {
        unsigned int u = __hip_atomic_load(&stage[(size_t)c * 3 + tid],
                                           __ATOMIC_RELAXED, __HIP_MEMORY_SCOPE_AGENT);
        sh.c.s_cent[tid] = __uint_as_float(u);
    }
    __syncthreads();

    // --- ball query (wave 0): ballot + prefix popcount, lowest indices
    // first (== reference sort+take-K), early exit at K. fp32-exact. ---
    if (wave == 0) {
        const float R2 = (float)(0.2 * 0.2);
        float cx = sh.c.s_cent[0], cy = sh.c.s_cent[1], cz = sh.c.s_cent[2];
        const float* pb = pos + (size_t)b * kP * 3;
        int cnt = 0;
        for (int p0 = 0; p0 < kP && cnt < kK; p0 += 64) {
            int idx = p0 + lane;
            float X = pb[idx * 3 + 0], Y = pb[idx * 3 + 1], Z = pb[idx * 3 + 2];
            float d2 = dist2(X, Y, Z, cx, cy, cz);
            bool in = d2 <= R2;
            unsigned long long mask = __ballot(in);
            int rank = __popcll(mask & ((1ull << lane) - 1ull));
            if (in && cnt + rank < kK) sh.c.s_nb[cnt + rank] = idx;
            cnt = min(cnt + (int)__popcll(mask), kK);
        }
        if (lane == 0) { sh.c.s_cnt = cnt; batch_out[c] = (float)b; }
    }
    __syncthreads();
    const int cnt = sh.c.s_cnt;

    // --- gather msg = [x_j (32) | pos_j - cent (3) | 0 pad] as fp16 ---
    for (int u = tid; u < kK * 36; u += 256) {
        int k = u / 36, f = u - k * 36;
        float v = 0.0f;
        if (k < cnt && f < 35) {
            int n = sh.c.s_nb[k];
            if (f < 32) v = x[((size_t)b * kP + n) * kF + f];
            else        v = pos[((size_t)b * kP + n) * 3 + (f - 32)] - sh.c.s_cent[f - 32];
        }
        sh.c.msg[k][f] = (_Float16)v;
    }
    __syncthreads();

    // layer 1: 35 -> 64 (fp16 dot2, fp32 accumulate)
    {
        int j = tid & 63, k0 = tid >> 6;
        h2f w[18];
#pragma unroll
        for (int p = 0; p < 17; ++p)
            w[p] = (h2f){(_Float16)W1[(2 * p) * 64 + j],
                         (_Float16)W1[(2 * p + 1) * 64 + j]};
        w[17] = (h2f){(_Float16)W1[34 * 64 + j], (_Float16)0.0f};
        float bb = b1[j];
#pragma unroll
        for (int kk = 0; kk < 16; ++kk) {
            int k = k0 * 16 + kk;
            float acc = bb;
#pragma unroll
            for (int p = 0; p < 18; ++p) {
                h2f a = *(const h2f*)&sh.c.msg[k][2 * p];
                acc = __builtin_amdgcn_fdot2(a, w[p], acc, false);
            }
            sh.c.h1[k][j] = (_Float16)fmaxf(acc, 0.0f);
        }
    }
    __syncthreads();

    // layer 2: 64 -> 64
    {
        int j = tid & 63, k0 = tid >> 6;
        h2f w[32];
#pragma unroll
        for (int p = 0; p < 32; ++p)
            w[p] = (h2f){(_Float16)W2[(2 * p) * 64 + j],
                         (_Float16)W2[(2 * p + 1) * 64 + j]};
        float bb = b2[j];
#pragma unroll
        for (int kk = 0; kk < 16; ++kk) {
            int k = k0 * 16 + kk;
            float acc = bb;
#pragma unroll
            for (int p = 0; p < 32; ++p) {
                h2f a = *(const h2f*)&sh.c.h1[k][2 * p];
                acc = __builtin_amdgcn_fdot2(a, w[p], acc, false);
            }
            sh.c.h2[k][j] = (_Float16)fmaxf(acc, 0.0f);
        }
    }
    __syncthreads();

    // layer 3: 64 -> 128, fused masked max over valid k
    {
        int j = tid & 127, k0 = tid >> 7;
        h2f w[32];
#pragma unroll
        for (int p = 0; p < 32; ++p)
            w[p] = (h2f){(_Float16)W3[(2 * p) * 128 + j],
                         (_Float16)W3[(2 * p + 1) * 128 + j]};
        float bb = b3[j];
        float best = -INFINITY;
        for (int kk = 0; kk < 32; ++kk) {
            int k = k0 * 32 + kk;      // wave-uniform bound
            if (k >= cnt) break;
            float acc = bb;
#pragma unroll
            for (int p = 0; p < 32; ++p) {
                h2f a = *(const h2f*)&sh.c.h2[k][2 * p];
                acc = __builtin_amdgcn_fdot2(a, w[p], acc, false);
            }
            best = fmaxf(best, fmaxf(acc, 0.0f));
        }
        sh.c.red[k0][j] = best;
    }
    __syncthreads();

    if (tid < kO) {
        float o = fmaxf(sh.c.red[0][tid], sh.c.red[1][tid]);   // cnt>=1 -> valid
        feat_out[(size_t)c * kO + tid] = o;
    }
}

// ---------------------------------------------------------------------------
extern "C" void kernel_launch(void* const* d_in, const int* in_sizes, int n_in,
                              void* d_out, int out_size, void* d_ws, size_t ws_size,
                              hipStream_t stream) {
    const float* pos = (const float*)d_in[0];
    // d_in[1] = batch (unused; implied by layout)
    const float* x  = (const float*)d_in[2];
    const float* W1 = (const float*)d_in[3];
    const float* b1 = (const float*)d_in[4];
    const float* W2 = (const float*)d_in[5];
    const float* b2 = (const float*)d_in[6];
    const float* W3 = (const float*)d_in[7];
    const float* b3 = (const float*)d_in[8];

    float* out = (float*)d_out;
    float* cent_out  = out;                                   // [B*M, 3]
    float* feat_out  = out + (size_t)kB * kM * 3;             // [B*M, 128]
    float* batch_out = out + (size_t)kB * kM * (3 + kO);      // [B*M]

    char* ws = (char*)d_ws;
    int* prog           = (int*)ws;                           // 128 ints (strided)
    unsigned int* stage = (unsigned int*)(ws + 512);          // B*M*3 uints

    init_kernel<<<1, 128, 0, stream>>>(prog);
    mega_kernel<<<kB + kB * kM, 256, 0, stream>>>(
        pos, x, W1, b1, W2, b2, W3, b3, stage, prog,
        cent_out, feat_out, batch_out);
}

// Round 14
// 2152.132 us; speedup vs baseline: 1.4965x; 1.0144x over previous
//
#include <hip/hip_runtime.h>
#include <stdint.h>
#include <math.h>

// Problem constants (from reference)
constexpr int kB = 8;      // clouds
constexpr int kP = 8192;   // points per cloud
constexpr int kF = 32;     // feature dim
constexpr int kM = 2048;   // centroids per cloud (P * 0.25)
constexpr int kK = 64;     // max neighbors
constexpr int kO = 128;    // output dim

typedef float v2f __attribute__((ext_vector_type(2)));
typedef _Float16 h8 __attribute__((ext_vector_type(8)));
typedef float f4v __attribute__((ext_vector_type(4)));

// Exact-f32 squared distance matching numpy: square elementwise, then
// sequential sum ((dx2+dy2)+dz2). contract(off) forbids fma fusion so this
// matches numpy bit-for-bit regardless of -ffp-contract=fast default.
__device__ __forceinline__ float dist2(float ax, float ay, float az,
                                       float bx, float by, float bz) {
#pragma clang fp contract(off)
    float dx = ax - bx, dy = ay - by, dz = az - bz;
    return (dx * dx + dy * dy) + dz * dz;
}

// One DPP step of a u64 (hi,lo) max-reduce. CTRL must be an immediate ->
// template parameter. bound_ctrl=true: invalid source lanes read 0, and
// (0,0) never wins because all real keys have klo = ~idx != 0.
template <int CTRL>
__device__ __forceinline__ void dpp_max_step(unsigned int& khi, unsigned int& klo) {
    unsigned int ohi = (unsigned int)__builtin_amdgcn_update_dpp(
        0, (int)khi, CTRL, 0xf, 0xf, true);
    unsigned int olo = (unsigned int)__builtin_amdgcn_update_dpp(
        0, (int)klo, CTRL, 0xf, 0xf, true);
    bool take = (ohi > khi) || (ohi == khi && olo > klo);
    khi = take ? ohi : khi;
    klo = take ? olo : klo;
}

// Zero the progress flags (d_ws is poisoned 0xAA before every launch).
__global__ void init_kernel(int* __restrict__ prog) {
    if (threadIdx.x < 128) prog[threadIdx.x] = 0;
}

// Role-union LDS. fps: big coord arrays (~100 KB). consumer: fp16 MFMA
// tiles + transposed fp16 weights (~121 KB). 1 block/CU either way.
union SharedU {
    struct {
        float sxp[kP], syp[kP], szp[kP];       // SoA cloud copy
        unsigned short widx[kM];               // winner index per iteration
        unsigned long long part[2][4];         // ping-pong wave partials
    } f;
    struct {
        _Float16 A0[256][72];                  // msg (cols 0..63), reused as h2
        _Float16 A1[256][72];                  // h1
        _Float16 Wt1[64][72];                  // W1^T [n][k], k>=35 zero
        _Float16 Wt2[64][72];                  // W2^T [n][k]
        _Float16 Wt3[128][72];                 // W3^T [n][k]
        float bias[256];                       // b1 | b2 | b3
        float red[4][4][128];                  // [centroid][quad][col]
        int   s_nb[4][kK];
        int   s_cnt[4];
    } c;
};

// ---------------------------------------------------------------------------
// Mega-kernel: producer/consumer overlap.
//  blocks 0..7    : FPS for cloud b (identical to r12; bit-exact).
//  blocks 8..4103 : 4 consecutive centroids of cloud b = i&7.
//                   Stage weights -> spin on prog[b] -> per-wave ball query
//                   -> per-wave gather -> per-wave fp16 MFMA MLP (fp32 acc)
//                   -> fused masked max -> cross-quad reduce -> feat_out.
// NOTE: __syncthreads() at EVERY consumer phase boundary. Wave-internal DS
// ordering is a HW property, but the compiler may hoist LDS loads (s_cnt is
// loop-invariant and never stored by this thread) above prior phases'
// stores — that hoist caused r13's garbage-index global OOB fault. Barriers
// are full compiler+HW fences; cost ~100cyc each vs ~15µs block.
// ---------------------------------------------------------------------------
__global__ __launch_bounds__(256, 1) void mega_kernel(
    const float* __restrict__ pos, const float* __restrict__ x,
    const float* __restrict__ W1, const float* __restrict__ b1,
    const float* __restrict__ W2, const float* __restrict__ b2,
    const float* __restrict__ W3, const float* __restrict__ b3,
    unsigned int* __restrict__ stage, int* __restrict__ prog,
    float* __restrict__ cent_out, float* __restrict__ feat_out,
    float* __restrict__ batch_out) {
    __shared__ SharedU sh;

    const int tid = threadIdx.x;
    const int wave = tid >> 6, lane = tid & 63;

    if (blockIdx.x < (unsigned)kB) {
        // ======================= FPS role (unchanged from r12) =============
        const int b = blockIdx.x;
        const float* pb = pos + (size_t)b * kP * 3;

        v2f px2[16], py2[16], pz2[16], dd2[16];
#pragma unroll
        for (int q = 0; q < 32; ++q) {
            int i = tid + q * 256;
            float X = pb[i * 3 + 0];
            float Y = pb[i * 3 + 1];
            float Z = pb[i * 3 + 2];
            sh.f.sxp[i] = X; sh.f.syp[i] = Y; sh.f.szp[i] = Z;
            if (q & 1) { px2[q >> 1].y = X; py2[q >> 1].y = Y; pz2[q >> 1].y = Z; }
            else       { px2[q >> 1].x = X; py2[q >> 1].x = Y; pz2[q >> 1].x = Z; }
        }
#pragma unroll
        for (int q = 0; q < 16; ++q) dd2[q] = (v2f){INFINITY, INFINITY};

        if (tid == 0) sh.f.widx[0] = 0;
        __syncthreads();

        float lx = sh.f.sxp[0], ly = sh.f.syp[0], lz = sh.f.szp[0];
        if (tid == 0) {
            size_t o = (size_t)(b * kM) * 3;
            __hip_atomic_store(&stage[o + 0], __float_as_uint(lx),
                               __ATOMIC_RELAXED, __HIP_MEMORY_SCOPE_AGENT);
            __hip_atomic_store(&stage[o + 1], __float_as_uint(ly),
                               __ATOMIC_RELAXED, __HIP_MEMORY_SCOPE_AGENT);
            __hip_atomic_store(&stage[o + 2], __float_as_uint(lz),
                               __ATOMIC_RELAXED, __HIP_MEMORY_SCOPE_AGENT);
            __hip_atomic_store(&prog[b * 16], 1,
                               __ATOMIC_RELEASE, __HIP_MEMORY_SCOPE_AGENT);
        }

        for (int m = 1; m < kM; ++m) {
            v2f lxv = {lx, lx}, lyv = {ly, ly}, lzv = {lz, lz};
#pragma unroll
            for (int q = 0; q < 16; ++q) {
#pragma clang fp contract(off)
                v2f dx = px2[q] - lxv;
                v2f dy = py2[q] - lyv;
                v2f dz = pz2[q] - lzv;
                v2f d2 = (dx * dx + dy * dy) + dz * dz;
                dd2[q].x = fminf(dd2[q].x, d2.x);
                dd2[q].y = fminf(dd2[q].y, d2.y);
            }

            v2f t0 = {fmaxf(dd2[0].x, dd2[0].y), fmaxf(dd2[1].x, dd2[1].y)};
            v2f t1 = {fmaxf(dd2[2].x, dd2[2].y), fmaxf(dd2[3].x, dd2[3].y)};
            v2f t2 = {fmaxf(dd2[4].x, dd2[4].y), fmaxf(dd2[5].x, dd2[5].y)};
            v2f t3 = {fmaxf(dd2[6].x, dd2[6].y), fmaxf(dd2[7].x, dd2[7].y)};
            v2f t4 = {fmaxf(dd2[8].x, dd2[8].y), fmaxf(dd2[9].x, dd2[9].y)};
            v2f t5 = {fmaxf(dd2[10].x, dd2[10].y), fmaxf(dd2[11].x, dd2[11].y)};
            v2f t6 = {fmaxf(dd2[12].x, dd2[12].y), fmaxf(dd2[13].x, dd2[13].y)};
            v2f t7 = {fmaxf(dd2[14].x, dd2[14].y), fmaxf(dd2[15].x, dd2[15].y)};
            float u0 = fmaxf(fmaxf(t0.x, t0.y), fmaxf(t1.x, t1.y));
            float u1 = fmaxf(fmaxf(t2.x, t2.y), fmaxf(t3.x, t3.y));
            float u2 = fmaxf(fmaxf(t4.x, t4.y), fmaxf(t5.x, t5.y));
            float u3 = fmaxf(fmaxf(t6.x, t6.y), fmaxf(t7.x, t7.y));
            float bv = fmaxf(fmaxf(u0, u1), fmaxf(u2, u3));

            int lqs[4];
#pragma unroll
            for (int g = 0; g < 4; ++g) {
                int t = 64;
#pragma unroll
                for (int s = 7; s >= 0; --s) {
                    int sl = g * 8 + s;
                    float v = (sl & 1) ? dd2[sl >> 1].y : dd2[sl >> 1].x;
                    t = (v == bv) ? sl : t;
                }
                lqs[g] = t;
            }
            int bq = lqs[3];
            bq = (lqs[2] < 64) ? lqs[2] : bq;
            bq = (lqs[1] < 64) ? lqs[1] : bq;
            bq = (lqs[0] < 64) ? lqs[0] : bq;

            unsigned int bidx = (unsigned int)(tid + bq * 256);
            unsigned int khi = __float_as_uint(bv);
            unsigned int klo = (unsigned int)(~bidx);

            dpp_max_step<0x111>(khi, klo);
            dpp_max_step<0x112>(khi, klo);
            dpp_max_step<0x114>(khi, klo);
            dpp_max_step<0x118>(khi, klo);
            dpp_max_step<0x142>(khi, klo);
            dpp_max_step<0x143>(khi, klo);
            if (lane == 63)
                sh.f.part[m & 1][wave] = ((unsigned long long)khi << 32) | klo;
            __syncthreads();

            unsigned long long k = sh.f.part[m & 1][0];
#pragma unroll
            for (int w = 1; w < 4; ++w) {
                unsigned long long o = sh.f.part[m & 1][w];
                if (o > k) k = o;
            }
            unsigned int wi = ~(unsigned int)k;
            lx = sh.f.sxp[wi]; ly = sh.f.syp[wi]; lz = sh.f.szp[wi];
            if (tid == 0) sh.f.widx[m] = (unsigned short)wi;

            if ((m & 31) == 31) {
                int m0 = m - 31;
                if (tid < 96) {
                    int mm = m0 + tid / 3;
                    int comp = tid % 3;
                    unsigned int w2 = (mm == m) ? wi
                                                : (unsigned int)sh.f.widx[mm];
                    float v = (comp == 0) ? sh.f.sxp[w2]
                            : (comp == 1) ? sh.f.syp[w2] : sh.f.szp[w2];
                    __hip_atomic_store(&stage[(size_t)(b * kM + mm) * 3 + comp],
                                       __float_as_uint(v),
                                       __ATOMIC_RELAXED, __HIP_MEMORY_SCOPE_AGENT);
                }
                __syncthreads();
                if (tid == 0)
                    __hip_atomic_store(&prog[b * 16], m + 1,
                                       __ATOMIC_RELEASE, __HIP_MEMORY_SCOPE_AGENT);
            }
        }
        __syncthreads();

#pragma unroll
        for (int q = 0; q < kM / 256; ++q) {
            int i = tid + q * 256;
            unsigned int wi = sh.f.widx[i];
            size_t o = (size_t)(b * kM + i) * 3;
            cent_out[o + 0] = sh.f.sxp[wi];
            cent_out[o + 1] = sh.f.syp[wi];
            cent_out[o + 2] = sh.f.szp[wi];
        }
        return;
    }

    // ======================= consumer role (G=4, MFMA) =====================
    const int i = (int)blockIdx.x - kB;
    const int b = i & 7;                 // cloud-rotated dispatch
    const int cl0 = (i >> 3) * 4;        // first of 4 centroids

    // --- stage weights/biases (independent of fps progress) ---
    for (int idx = tid; idx < 64 * 64; idx += 256) {
        int n = idx & 63, kk = idx >> 6;
        sh.c.Wt1[n][kk] = (_Float16)((kk < 35) ? W1[kk * 64 + n] : 0.0f);
        sh.c.Wt2[n][kk] = (_Float16)W2[kk * 64 + n];
    }
    for (int idx = tid; idx < 64 * 128; idx += 256) {
        int n = idx & 127, kk = idx >> 7;
        sh.c.Wt3[n][kk] = (_Float16)W3[kk * 128 + n];
    }
    sh.c.bias[tid] = (tid < 64) ? b1[tid] : (tid < 128) ? b2[tid - 64]
                                                        : b3[tid - 128];

    // --- wait until fps has published all 4 centroids ---
    if (tid == 0) {
        int p;
        while ((p = __hip_atomic_load(&prog[b * 16], __ATOMIC_ACQUIRE,
                                      __HIP_MEMORY_SCOPE_AGENT)) < cl0 + 4) {
            if (cl0 + 4 - p > 128) __builtin_amdgcn_s_sleep(64);
            else                   __builtin_amdgcn_s_sleep(8);
        }
    }
    __syncthreads();   // orders weight staging + spin vs everything below

    // --- ball query: wave w owns centroid cl0+w (fp32-exact) ---
    const int c = b * kM + cl0 + wave;
    float cx = __uint_as_float(__hip_atomic_load(&stage[(size_t)c * 3 + 0],
                   __ATOMIC_RELAXED, __HIP_MEMORY_SCOPE_AGENT));
    float cy = __uint_as_float(__hip_atomic_load(&stage[(size_t)c * 3 + 1],
                   __ATOMIC_RELAXED, __HIP_MEMORY_SCOPE_AGENT));
    float cz = __uint_as_float(__hip_atomic_load(&stage[(size_t)c * 3 + 2],
                   __ATOMIC_RELAXED, __HIP_MEMORY_SCOPE_AGENT));
    {
        const float R2 = (float)(0.2 * 0.2);
        const float* pb = pos + (size_t)b * kP * 3;
        int cnt = 0;
        for (int p0 = 0; p0 < kP && cnt < kK; p0 += 64) {
            int idx = p0 + lane;
            float X = pb[idx * 3 + 0], Y = pb[idx * 3 + 1], Z = pb[idx * 3 + 2];
            float d2 = dist2(X, Y, Z, cx, cy, cz);
            bool in = d2 <= R2;
            unsigned long long mask = __ballot(in);
            int rank = __popcll(mask & ((1ull << lane) - 1ull));
            if (in && cnt + rank < kK) sh.c.s_nb[wave][cnt + rank] = idx;
            cnt = min(cnt + (int)__popcll(mask), kK);
        }
        if (lane == 0) { sh.c.s_cnt[wave] = cnt; batch_out[c] = (float)b; }
    }
    __syncthreads();   // fence: s_nb/s_cnt stores -> reads (compiler+HW)
    const int cntw = sh.c.s_cnt[wave];

    // --- gather: thread = row tid = (wave,lane); msg cols 0..63 (35 used) ---
    {
        int k = lane;
        if (k < cntw) {
            int n = sh.c.s_nb[wave][k];
            const float4* xr4 = (const float4*)(x + ((size_t)b * kP + n) * kF);
#pragma unroll
            for (int t = 0; t < 4; ++t) {
                float4 a4 = xr4[2 * t], c4 = xr4[2 * t + 1];
                h8 o = {(_Float16)a4.x, (_Float16)a4.y, (_Float16)a4.z,
                        (_Float16)a4.w, (_Float16)c4.x, (_Float16)c4.y,
                        (_Float16)c4.z, (_Float16)c4.w};
                *(h8*)&sh.c.A0[tid][t * 8] = o;
            }
            float dx = pos[((size_t)b * kP + n) * 3 + 0] - cx;
            float dy = pos[((size_t)b * kP + n) * 3 + 1] - cy;
            float dz = pos[((size_t)b * kP + n) * 3 + 2] - cz;
            h8 o4 = {(_Float16)dx, (_Float16)dy, (_Float16)dz,
                     (_Float16)0.f, (_Float16)0.f, (_Float16)0.f,
                     (_Float16)0.f, (_Float16)0.f};
            *(h8*)&sh.c.A0[tid][32] = o4;
            h8 z = {};
            *(h8*)&sh.c.A0[tid][40] = z;
            *(h8*)&sh.c.A0[tid][48] = z;
            *(h8*)&sh.c.A0[tid][56] = z;
        } else {
            h8 z = {};
#pragma unroll
            for (int t = 0; t < 8; ++t) *(h8*)&sh.c.A0[tid][t * 8] = z;
        }
    }
    __syncthreads();   // fence: A0 stores -> MFMA A-fragment reads

    const int m16 = lane & 15, quad = lane >> 4;

    // --- layer 1: A0(msg) x Wt1 -> A1(h1), N=64, K=64 (fp16 MFMA, f32 acc)
    {
        h8 bf[4][2];
#pragma unroll
        for (int nt = 0; nt < 4; ++nt)
#pragma unroll
            for (int kc = 0; kc < 2; ++kc)
                bf[nt][kc] = *(const h8*)&sh.c.Wt1[nt * 16 + m16][kc * 32 + quad * 8];
#pragma unroll
        for (int mt = 0; mt < 4; ++mt) {
            int m0 = wave * 64 + mt * 16;
            h8 a0 = *(const h8*)&sh.c.A0[m0 + m16][quad * 8];
            h8 a1 = *(const h8*)&sh.c.A0[m0 + m16][32 + quad * 8];
#pragma unroll
            for (int nt = 0; nt < 4; ++nt) {
                f4v acc = {0.f, 0.f, 0.f, 0.f};
                acc = __builtin_amdgcn_mfma_f32_16x16x32_f16(a0, bf[nt][0], acc, 0, 0, 0);
                acc = __builtin_amdgcn_mfma_f32_16x16x32_f16(a1, bf[nt][1], acc, 0, 0, 0);
                int n = nt * 16 + m16;
                float bb = sh.c.bias[n];
#pragma unroll
                for (int r = 0; r < 4; ++r)
                    sh.c.A1[m0 + quad * 4 + r][n] =
                        (_Float16)fmaxf(acc[r] + bb, 0.0f);
            }
        }
    }
    __syncthreads();   // fence: A1 stores -> layer-2 A-fragment reads

    // --- layer 2: A1(h1) x Wt2 -> A0(h2), N=64, K=64 ---
    {
        h8 bf[4][2];
#pragma unroll
        for (int nt = 0; nt < 4; ++nt)
#pragma unroll
            for (int kc = 0; kc < 2; ++kc)
                bf[nt][kc] = *(const h8*)&sh.c.Wt2[nt * 16 + m16][kc * 32 + quad * 8];
#pragma unroll
        for (int mt = 0; mt < 4; ++mt) {
            int m0 = wave * 64 + mt * 16;
            h8 a0 = *(const h8*)&sh.c.A1[m0 + m16][quad * 8];
            h8 a1 = *(const h8*)&sh.c.A1[m0 + m16][32 + quad * 8];
#pragma unroll
            for (int nt = 0; nt < 4; ++nt) {
                f4v acc = {0.f, 0.f, 0.f, 0.f};
                acc = __builtin_amdgcn_mfma_f32_16x16x32_f16(a0, bf[nt][0], acc, 0, 0, 0);
                acc = __builtin_amdgcn_mfma_f32_16x16x32_f16(a1, bf[nt][1], acc, 0, 0, 0);
                int n = nt * 16 + m16;
                float bb = sh.c.bias[64 + n];
#pragma unroll
                for (int r = 0; r < 4; ++r)
                    sh.c.A0[m0 + quad * 4 + r][n] =
                        (_Float16)fmaxf(acc[r] + bb, 0.0f);
            }
        }
    }
    __syncthreads();   // fence: A0(h2) stores -> layer-3 A-fragment reads

    // --- layer 3: A0(h2) x Wt3, N=128, K=64; fused relu+bias+masked max ---
    {
        h8 bf[8][2];
#pragma unroll
        for (int nt = 0; nt < 8; ++nt)
#pragma unroll
            for (int kc = 0; kc < 2; ++kc)
                bf[nt][kc] = *(const h8*)&sh.c.Wt3[nt * 16 + m16][kc * 32 + quad * 8];
        float best[8];
#pragma unroll
        for (int nt = 0; nt < 8; ++nt) best[nt] = -INFINITY;
#pragma unroll
        for (int mt = 0; mt < 4; ++mt) {
            int m0 = wave * 64 + mt * 16;
            h8 a0 = *(const h8*)&sh.c.A0[m0 + m16][quad * 8];
            h8 a1 = *(const h8*)&sh.c.A0[m0 + m16][32 + quad * 8];
#pragma unroll
            for (int nt = 0; nt < 8; ++nt) {
                f4v acc = {0.f, 0.f, 0.f, 0.f};
                acc = __builtin_amdgcn_mfma_f32_16x16x32_f16(a0, bf[nt][0], acc, 0, 0, 0);
                acc = __builtin_amdgcn_mfma_f32_16x16x32_f16(a1, bf[nt][1], acc, 0, 0, 0);
                int n = nt * 16 + m16;
                float bb = sh.c.bias[128 + n];
#pragma unroll
                for (int r = 0; r < 4; ++r) {
                    int krow = mt * 16 + quad * 4 + r;   // row within centroid
                    float v = fmaxf(acc[r] + bb, 0.0f);
                    if (krow < cntw) best[nt] = fmaxf(best[nt], v);
                }
            }
        }
#pragma unroll
        for (int nt = 0; nt < 8; ++nt)
            sh.c.red[wave][quad][nt * 16 + m16] = best[nt];
    }
    __syncthreads();

    // --- final: max over 4 quads, write feat_out ---
    {
        int w2 = tid >> 6, n = tid & 63;
#pragma unroll
        for (int h = 0; h < 2; ++h) {
            int n2 = n + h * 64;
            float o = fmaxf(fmaxf(sh.c.red[w2][0][n2], sh.c.red[w2][1][n2]),
                            fmaxf(sh.c.red[w2][2][n2], sh.c.red[w2][3][n2]));
            feat_out[(size_t)(b * kM + cl0 + w2) * kO + n2] = o;
        }
    }
}

// ---------------------------------------------------------------------------
extern "C" void kernel_launch(void* const* d_in, const int* in_sizes, int n_in,
                              void* d_out, int out_size, void* d_ws, size_t ws_size,
                              hipStream_t stream) {
    const float* pos = (const float*)d_in[0];
    // d_in[1] = batch (unused; implied by layout)
    const float* x  = (const float*)d_in[2];
    const float* W1 = (const float*)d_in[3];
    const float* b1 = (const float*)d_in[4];
    const float* W2 = (const float*)d_in[5];
    const float* b2 = (const float*)d_in[6];
    const float* W3 = (const float*)d_in[7];
    const float* b3 = (const float*)d_in[8];

    float* out = (float*)d_out;
    float* cent_out  = out;                                   // [B*M, 3]
    float* feat_out  = out + (size_t)kB * kM * 3;             // [B*M, 128]
    float* batch_out = out + (size_t)kB * kM * (3 + kO);      // [B*M]

    char* ws = (char*)d_ws;
    int* prog           = (int*)ws;                           // 128 ints (strided)
    unsigned int* stage = (unsigned int*)(ws + 512);          // B*M*3 uints

    init_kernel<<<1, 128, 0, stream>>>(prog);
    mega_kernel<<<kB + (kB * kM) / 4, 256, 0, stream>>>(
        pos, x, W1, b1, W2, b2, W3, b3, stage, prog,
        cent_out, feat_out, batch_out);
}